// Round 6
// baseline (701.017 us; speedup 1.0000x reference)
//
#include <hip/hip_runtime.h>
#include <hip/hip_bf16.h>

// ChildSumTreeLSTM, fp32 in/out, depth=17, N=2^18-1, D_IN=H=128.
// R7: rcp-based sigm/tanh.
// R11: k_lvl (task = 32 parents x 16 cols, waves split K=32, LDS reduce,
//      wave0 epilogue) for small levels -> 511 us.
// R12: kill the latency-structured k_pair entirely. k_leaf = pure throughput
//      x@W GEMM for the leaf level (writes h bf16 / c fp32 to HBM, ~100 MB
//      ~25 us of BW instead of ~150 us of dependent-chain latency); the
//      PROVEN k_lvl (unchanged from R11) now runs every level 16..0.
// Weights: W plain bf16, U split-2 hi/lo bf16 (pre-swizzled to B-frag order).
// h global bf16, c global fp32. Shifted rows: row = node+1.

typedef __bf16 bf16_t;
typedef __bf16 bf16x8 __attribute__((ext_vector_type(8)));
typedef float  f32x4  __attribute__((ext_vector_type(4)));

#define MFMA16(a, b, c) __builtin_amdgcn_mfma_f32_16x16x32_bf16((a), (b), (c), 0, 0, 0)

__device__ __forceinline__ float rcp_(float x) { return __builtin_amdgcn_rcpf(x); }
// bf16-rounded outputs: 1-ulp v_rcp_f32 error is invisible.
__device__ __forceinline__ float sigm(float x) { return rcp_(1.0f + __expf(-x)); }
__device__ __forceinline__ float tanh_(float x) {
    float a = fabsf(x);
    float e = __expf(2.0f * a);
    float t = fmaf(-2.0f, rcp_(e + 1.0f), 1.0f);
    return copysignf(t, x);
}

__device__ __forceinline__ void cvt16(const float* __restrict__ src, bf16_t* __restrict__ dst)
{
    float tmp[16];
    *(float4*)&tmp[0]  = ((const float4*)src)[0];
    *(float4*)&tmp[4]  = ((const float4*)src)[1];
    *(float4*)&tmp[8]  = ((const float4*)src)[2];
    *(float4*)&tmp[12] = ((const float4*)src)[3];
    bf16_t b[16];
#pragma unroll
    for (int j = 0; j < 16; j++) b[j] = (bf16_t)tmp[j];
    *(bf16x8*)&dst[0] = *(bf16x8*)&b[0];
    *(bf16x8*)&dst[8] = *(bf16x8*)&b[8];
}

__device__ __forceinline__ void zero16(bf16_t* __restrict__ dst)
{
    bf16x8 z = (bf16x8)(bf16_t)0.f;
    *(bf16x8*)&dst[0] = z;
    *(bf16x8*)&dst[8] = z;
}

// SW layout (bf16 elems): W g (0=Wi 1=Wf 2=Wo 3=Wu) at g*16384, plain.
// U u (0=Ui 1=Uf 2=Uo 3=Uu) at 65536 + u*32768 (hi), +16384 (lo).
// idx = ((nt*4+kb)*64 + lane)*8 + j ; elem = M[kb*32+(lane>>4)*8+j][nt*16+(lane&15)]
__global__ __launch_bounds__(256)
void k_prep(const float* __restrict__ Wi, const float* __restrict__ Wf,
            const float* __restrict__ Wo, const float* __restrict__ Wu,
            const float* __restrict__ Ui, const float* __restrict__ Uf,
            const float* __restrict__ Uo, const float* __restrict__ Uu,
            bf16_t* __restrict__ SW)
{
    int b = blockIdx.x;
    const float* src;
    switch (b) {
        case 0: src = Wi; break; case 1: src = Wf; break;
        case 2: src = Wo; break; case 3: src = Wu; break;
        case 4: src = Ui; break; case 5: src = Uf; break;
        case 6: src = Uo; break; default: src = Uu; break;
    }
    if (b < 4) {
        bf16_t* hi = SW + (size_t)b * 16384;
        for (int idx = threadIdx.x; idx < 16384; idx += 256) {
            int j = idx & 7, ln = (idx >> 3) & 63, kb = (idx >> 9) & 3, nt = idx >> 11;
            int k = kb * 32 + (ln >> 4) * 8 + j;
            int n = nt * 16 + (ln & 15);
            hi[idx] = (bf16_t)src[k * 128 + n];
        }
    } else {
        bf16_t* hi = SW + 65536 + (size_t)(b - 4) * 32768;
        bf16_t* lo = hi + 16384;
        for (int idx = threadIdx.x; idx < 16384; idx += 256) {
            int j = idx & 7, ln = (idx >> 3) & 63, kb = (idx >> 9) & 3, nt = idx >> 11;
            int k = kb * 32 + (ln >> 4) * 8 + j;
            int n = nt * 16 + (ln & 15);
            float w = src[k * 128 + n];
            bf16_t hh = (bf16_t)w;
            hi[idx] = hh;
            lo[idx] = (bf16_t)(w - (float)hh);
        }
    }
}

// ---------------------------------------------------------------------------
// k_leaf: pure throughput x@W GEMM for the leaf level (np = 2^depth nodes).
// Block = 32 rows x 128 cols, 4 waves x 2 col-tiles, 3 gates (i,o,u).
// Epilogue in-lane, then LDS-transpose for fully coalesced global stores:
// h bf16 (uint4 x2 per thread), c fp32 (float4 x4 per thread).
__global__ __launch_bounds__(256, 4)
void k_leaf(const float* __restrict__ x, const bf16_t* __restrict__ SW,
            const float* __restrict__ bi, const float* __restrict__ bo,
            const float* __restrict__ bu,
            bf16_t* __restrict__ H, float* __restrict__ C, int np)
{
    __shared__ __align__(16) char smem[34816];
    bf16_t (*XA)[136] = (bf16_t(*)[136])smem;           //  8704
    bf16_t (*Hd)[136] = (bf16_t(*)[136])(smem + 8704);  //  8704
    float  (*Cd)[136] = (float(*)[136])(smem + 17408);  // 17408 (544B rows, 16B-aligned)

    const int tid = threadIdx.x;
    const int srow = np + 32 * blockIdx.x;   // shifted global row base
    {
        int r = tid >> 3, cb = (tid & 7) * 16;
        cvt16(x + (size_t)(srow - 1 + r) * 128 + cb, &XA[r][cb]);
    }
    __syncthreads();
    const int wave = tid >> 6, lane = tid & 63;
    const int quad = lane >> 4, lc = lane & 15;

    f32x4 aI[2][2], aO[2][2], aU[2][2];
#pragma unroll
    for (int nt = 0; nt < 2; nt++)
#pragma unroll
        for (int mt = 0; mt < 2; mt++) {
            aI[nt][mt] = (f32x4){0.f, 0.f, 0.f, 0.f};
            aO[nt][mt] = (f32x4){0.f, 0.f, 0.f, 0.f};
            aU[nt][mt] = (f32x4){0.f, 0.f, 0.f, 0.f};
        }
#pragma unroll
    for (int kb = 0; kb < 4; kb++) {
        const int k0 = kb * 32 + quad * 8;
        bf16x8 a0 = *(const bf16x8*)&XA[lc][k0];
        bf16x8 a1 = *(const bf16x8*)&XA[16 + lc][k0];
#pragma unroll
        for (int nt = 0; nt < 2; nt++) {
            const size_t boff = ((size_t)((2 * wave + nt) * 4 + kb) * 64 + lane) * 8;
            bf16x8 bWi = *(const bf16x8*)(SW + boff);
            bf16x8 bWo = *(const bf16x8*)(SW + 32768 + boff);
            bf16x8 bWu = *(const bf16x8*)(SW + 49152 + boff);
            aI[nt][0] = MFMA16(a0, bWi, aI[nt][0]);
            aI[nt][1] = MFMA16(a1, bWi, aI[nt][1]);
            aO[nt][0] = MFMA16(a0, bWo, aO[nt][0]);
            aO[nt][1] = MFMA16(a1, bWo, aO[nt][1]);
            aU[nt][0] = MFMA16(a0, bWu, aU[nt][0]);
            aU[nt][1] = MFMA16(a1, bWu, aU[nt][1]);
        }
    }
    __syncthreads();   // XA reads done (Hd/Cd are separate regions, but keep order sane)
#pragma unroll
    for (int nt = 0; nt < 2; nt++) {
        const int col = (2 * wave + nt) * 16 + lc;
        float bii = bi[col], boi = bo[col], bui = bu[col];
#pragma unroll
        for (int mt = 0; mt < 2; mt++)
#pragma unroll
            for (int r = 0; r < 4; r++) {
                float iv = sigm(aI[nt][mt][r] + bii);
                float ov = sigm(aO[nt][mt][r] + boi);
                float uv = tanh_(aU[nt][mt][r] + bui);
                float cv = iv * uv;
                int pl = mt * 16 + quad * 4 + r;
                Hd[pl][col] = (bf16_t)(ov * tanh_(cv));
                Cd[pl][col] = cv;
            }
    }
    __syncthreads();
    {
        int r = tid >> 3, cb = (tid & 7) * 16;
        uint4* dh = (uint4*)(H + (size_t)(srow + r) * 128 + cb);
        dh[0] = *(uint4*)&Hd[r][cb];
        dh[1] = *(uint4*)&Hd[r][cb + 8];
        float4* dc = (float4*)(C + (size_t)(srow + r) * 128 + cb);
        const float4* sc4 = (const float4*)&Cd[r][cb];
        dc[0] = sc4[0]; dc[1] = sc4[1]; dc[2] = sc4[2]; dc[3] = sc4[3];
    }
}

// ---------------------------------------------------------------------------
// k_lvl: ONE level (np = 2^l parents). Task/block = (mt, ct): 32 parents x
// 16 cols. Waves split K (wave = one K=32 slice), partials reduced via LDS,
// wave 0 runs the epilogue and writes h (bf16) / c (f32) straight to global.
// Per-task dependent weight chain = 12 parallel loads.
// LDS: PR[12][4][64] f32x4 @0 (49152) | XA[32][136] @49152 | CH[64][136]
// @57856 | SC[32][17] f32 aliases PR head (wave-0 private, post-reduce).
// (Unchanged from R11 — verified.)
__global__ __launch_bounds__(256, 2)
void k_lvl(const float* __restrict__ x, const bf16_t* __restrict__ SW,
           const float* __restrict__ bi, const float* __restrict__ bf_,
           const float* __restrict__ bo, const float* __restrict__ bu,
           bf16_t* H, float* C, int np)
{
    __shared__ __align__(16) char smem[75264];
    f32x4  (*PR)[4][64] = (f32x4(*)[4][64])smem;
    bf16_t (*XA)[136]   = (bf16_t(*)[136])(smem + 49152);
    bf16_t (*CH)[136]   = (bf16_t(*)[136])(smem + 57856);
    float  (*SC)[17]    = (float(*)[17])smem;

    const int tid = threadIdx.x;
    const int wave = tid >> 6, lane = tid & 63;
    const int quad = lane >> 4, lc = lane & 15;

    const int task = blockIdx.x;
    const int ct = task & 7, mt = task >> 3;
    int valid = np - 32 * mt; if (valid > 32) valid = 32;
    if (valid <= 0) return;
    const int prow = np + 32 * mt;        // shifted parent row base
    const int crow = 2 * np + 64 * mt;    // shifted children row base

    {   // stage XA
        int r = tid >> 3, cb = (tid & 7) * 16;
        if (r < valid) cvt16(x + (size_t)(prow - 1 + r) * 128 + cb, &XA[r][cb]);
        else           zero16(&XA[r][cb]);
    }
    {   // stage CH (64 children-h rows, bf16)
        int r = tid >> 2, cb = (tid & 3) * 32;
        if (r < 2 * valid) {
            const uint4* src = (const uint4*)(H + (size_t)(crow + r) * 128 + cb);
            *(uint4*)&CH[r][cb]      = src[0];
            *(uint4*)&CH[r][cb + 8]  = src[1];
            *(uint4*)&CH[r][cb + 16] = src[2];
            *(uint4*)&CH[r][cb + 24] = src[3];
        } else {
            uint4 z = {0u, 0u, 0u, 0u};
            *(uint4*)&CH[r][cb]      = z;
            *(uint4*)&CH[r][cb + 8]  = z;
            *(uint4*)&CH[r][cb + 16] = z;
            *(uint4*)&CH[r][cb + 24] = z;
        }
    }
    __syncthreads();

    // K-slice kb = wave (K=32): 12 weight frags (all independent), 28 MFMAs
    f32x4 z4 = (f32x4){0.f, 0.f, 0.f, 0.f};
    f32x4 aI0 = z4, aI1 = z4, aXf0 = z4, aXf1 = z4;
    f32x4 aO0 = z4, aO1 = z4, aU0 = z4, aU1 = z4;
    f32x4 aF0 = z4, aF1 = z4, aF2 = z4, aF3 = z4;
    {
        const int k0 = wave * 32 + quad * 8;
        bf16x8 xa0 = *(const bf16x8*)&XA[lc][k0];
        bf16x8 xa1 = *(const bf16x8*)&XA[16 + lc][k0];
        bf16x8 h00 = *(const bf16x8*)&CH[2 * lc][k0];
        bf16x8 h01 = *(const bf16x8*)&CH[2 * lc + 1][k0];
        bf16x8 h10 = *(const bf16x8*)&CH[2 * lc + 32][k0];
        bf16x8 h11 = *(const bf16x8*)&CH[2 * lc + 33][k0];
        bf16x8 at0, at1;
#pragma unroll
        for (int j = 0; j < 8; j++) {
            at0[j] = (bf16_t)((float)h00[j] + (float)h01[j]);
            at1[j] = (bf16_t)((float)h10[j] + (float)h11[j]);
        }
        bf16x8 ac0 = *(const bf16x8*)&CH[lc][k0];
        bf16x8 ac1 = *(const bf16x8*)&CH[16 + lc][k0];
        bf16x8 ac2 = *(const bf16x8*)&CH[32 + lc][k0];
        bf16x8 ac3 = *(const bf16x8*)&CH[48 + lc][k0];

        const size_t boff = ((size_t)(ct * 4 + wave) * 64 + lane) * 8;
        bf16x8 bWi = *(const bf16x8*)(SW + boff);
        bf16x8 bWf = *(const bf16x8*)(SW + 16384 + boff);
        bf16x8 bWo = *(const bf16x8*)(SW + 32768 + boff);
        bf16x8 bWu = *(const bf16x8*)(SW + 49152 + boff);
        const bf16_t* Ub = SW + 65536;
        bf16x8 bIh = *(const bf16x8*)(Ub + boff);
        bf16x8 bIl = *(const bf16x8*)(Ub + 16384 + boff);
        bf16x8 bFh = *(const bf16x8*)(Ub + 32768 + boff);
        bf16x8 bFl = *(const bf16x8*)(Ub + 49152 + boff);
        bf16x8 bOh = *(const bf16x8*)(Ub + 65536 + boff);
        bf16x8 bOl = *(const bf16x8*)(Ub + 81920 + boff);
        bf16x8 bUh = *(const bf16x8*)(Ub + 98304 + boff);
        bf16x8 bUl = *(const bf16x8*)(Ub + 114688 + boff);

        aI0  = MFMA16(xa0, bWi, aI0);  aI1  = MFMA16(xa1, bWi, aI1);
        aXf0 = MFMA16(xa0, bWf, aXf0); aXf1 = MFMA16(xa1, bWf, aXf1);
        aO0  = MFMA16(xa0, bWo, aO0);  aO1  = MFMA16(xa1, bWo, aO1);
        aU0  = MFMA16(xa0, bWu, aU0);  aU1  = MFMA16(xa1, bWu, aU1);
        aI0 = MFMA16(at0, bIh, aI0); aI0 = MFMA16(at0, bIl, aI0);
        aI1 = MFMA16(at1, bIh, aI1); aI1 = MFMA16(at1, bIl, aI1);
        aO0 = MFMA16(at0, bOh, aO0); aO0 = MFMA16(at0, bOl, aO0);
        aO1 = MFMA16(at1, bOh, aO1); aO1 = MFMA16(at1, bOl, aO1);
        aU0 = MFMA16(at0, bUh, aU0); aU0 = MFMA16(at0, bUl, aU0);
        aU1 = MFMA16(at1, bUh, aU1); aU1 = MFMA16(at1, bUl, aU1);
        aF0 = MFMA16(ac0, bFh, aF0); aF0 = MFMA16(ac0, bFl, aF0);
        aF1 = MFMA16(ac1, bFh, aF1); aF1 = MFMA16(ac1, bFl, aF1);
        aF2 = MFMA16(ac2, bFh, aF2); aF2 = MFMA16(ac2, bFl, aF2);
        aF3 = MFMA16(ac3, bFh, aF3); aF3 = MFMA16(ac3, bFl, aF3);
    }
    if (wave != 0) {
        PR[0][wave][lane]  = aI0;  PR[1][wave][lane]  = aI1;
        PR[2][wave][lane]  = aXf0; PR[3][wave][lane]  = aXf1;
        PR[4][wave][lane]  = aO0;  PR[5][wave][lane]  = aO1;
        PR[6][wave][lane]  = aU0;  PR[7][wave][lane]  = aU1;
        PR[8][wave][lane]  = aF0;  PR[9][wave][lane]  = aF1;
        PR[10][wave][lane] = aF2;  PR[11][wave][lane] = aF3;
    }
    __syncthreads();
    if (wave == 0) {
        aI0  += PR[0][1][lane]  + PR[0][2][lane]  + PR[0][3][lane];
        aI1  += PR[1][1][lane]  + PR[1][2][lane]  + PR[1][3][lane];
        aXf0 += PR[2][1][lane]  + PR[2][2][lane]  + PR[2][3][lane];
        aXf1 += PR[3][1][lane]  + PR[3][2][lane]  + PR[3][3][lane];
        aO0  += PR[4][1][lane]  + PR[4][2][lane]  + PR[4][3][lane];
        aO1  += PR[5][1][lane]  + PR[5][2][lane]  + PR[5][3][lane];
        aU0  += PR[6][1][lane]  + PR[6][2][lane]  + PR[6][3][lane];
        aU1  += PR[7][1][lane]  + PR[7][2][lane]  + PR[7][3][lane];
        aF0  += PR[8][1][lane]  + PR[8][2][lane]  + PR[8][3][lane];
        aF1  += PR[9][1][lane]  + PR[9][2][lane]  + PR[9][3][lane];
        aF2  += PR[10][1][lane] + PR[10][2][lane] + PR[10][3][lane];
        aF3  += PR[11][1][lane] + PR[11][2][lane] + PR[11][3][lane];

        const int colg = ct * 16 + lc;
        // prefetch children c (issued early, latency hides under VALU)
        float c0v[4][2], c1v[4][2];
#pragma unroll
        for (int m2 = 0; m2 < 4; m2++)
#pragma unroll
            for (int pi = 0; pi < 2; pi++) {
                int pl = m2 * 8 + quad * 2 + pi;
                size_t cr = (size_t)(crow + 2 * pl) * 128 + colg;
                c0v[m2][pi] = C[cr];
                c1v[m2][pi] = C[cr + 128];
            }
        // xf (+bias) exchange (wave-private LDS, in-wave RAW only)
        float bfv = bf_[colg];
#pragma unroll
        for (int r = 0; r < 4; r++) {
            SC[quad * 4 + r][lc]      = aXf0[r] + bfv;
            SC[16 + quad * 4 + r][lc] = aXf1[r] + bfv;
        }
        // f-path: read xf at child-lane row, write S back in place
#define NS_FPATH(M2, AF)                                            \
        _Pragma("unroll")                                           \
        for (int pi = 0; pi < 2; pi++) {                            \
            int pl = M2 * 8 + quad * 2 + pi;                        \
            float xf = SC[pl][lc];                                  \
            float f0 = sigm(xf + AF[2 * pi]);                       \
            float f1 = sigm(xf + AF[2 * pi + 1]);                   \
            SC[pl][lc] = f0 * c0v[M2][pi] + f1 * c1v[M2][pi];       \
        }
        NS_FPATH(0, aF0) NS_FPATH(1, aF1) NS_FPATH(2, aF2) NS_FPATH(3, aF3)
#undef NS_FPATH
        // i/o/u + cell update, store straight to global
        float bii = bi[colg], boi = bo[colg], bui = bu[colg];
#define NS_IOU(MT, AI, AO, AU)                                      \
        _Pragma("unroll")                                           \
        for (int r = 0; r < 4; r++) {                               \
            int pl = MT * 16 + quad * 4 + r;                        \
            float iv = sigm(AI[r] + bii);                           \
            float ov = sigm(AO[r] + boi);                           \
            float uv = tanh_(AU[r] + bui);                          \
            float cv = iv * uv + SC[pl][lc];                        \
            if (pl < valid) {                                       \
                H[(size_t)(prow + pl) * 128 + colg] = (bf16_t)(ov * tanh_(cv)); \
                C[(size_t)(prow + pl) * 128 + colg] = cv;           \
            }                                                       \
        }
        NS_IOU(0, aI0, aO0, aU0)
        NS_IOU(1, aI1, aO1, aU1)
#undef NS_IOU
    }
}

__global__ __launch_bounds__(256)
void k_out(const bf16_t* __restrict__ H, const float* __restrict__ C,
           float* __restrict__ out)
{
    int t = threadIdx.x;
    if (t < 128)      out[t] = (float)H[128 + t];   // shifted row 1 = root
    else if (t < 256) out[t] = C[t];                // C[128 + (t-128)]
}

// ---------------------------------------------------------------------------
extern "C" void kernel_launch(void* const* d_in, const int* in_sizes, int n_in,
                              void* d_out, int out_size, void* d_ws, size_t ws_size,
                              hipStream_t stream)
{
    const float* x   = (const float*)d_in[0];
    const float* Wi  = (const float*)d_in[1];
    const float* bi  = (const float*)d_in[2];
    const float* Ui  = (const float*)d_in[3];
    const float* Wf  = (const float*)d_in[4];
    const float* bf_ = (const float*)d_in[5];
    const float* Uf  = (const float*)d_in[6];
    const float* Wo  = (const float*)d_in[7];
    const float* bo  = (const float*)d_in[8];
    const float* Uo  = (const float*)d_in[9];
    const float* Wu  = (const float*)d_in[10];
    const float* bu  = (const float*)d_in[11];
    const float* Uu  = (const float*)d_in[12];

    int Ntot  = in_sizes[0] / 128;
    int depth = 31 - __builtin_clz((unsigned)(Ntot + 1)) - 1;

    // workspace: SW 384 KB | H bf16 (Ntot+1)*128 | C fp32 (Ntot+1)*128
    char* w = (char*)d_ws;
    bf16_t* SW = (bf16_t*)w;  w += 393216;
    bf16_t* H  = (bf16_t*)w;  w += (size_t)(Ntot + 1) * 128 * sizeof(bf16_t);
    float*  C  = (float*)w;

    k_prep<<<8, 256, 0, stream>>>(Wi, Wf, Wo, Wu, Ui, Uf, Uo, Uu, SW);

    // leaves: pure x@W throughput GEMM -> global h/c
    int NL = 1 << depth;
    k_leaf<<<NL / 32, 256, 0, stream>>>(x, SW, bi, bo, bu, H, C, NL);

    // every internal level: latency-optimized K-split tasks
    for (int l = depth - 1; l >= 0; l--) {
        int np = 1 << l;
        int nmt = (np + 31) / 32;
        k_lvl<<<nmt * 8, 256, 0, stream>>>(x, SW, bi, bf_, bo, bu, H, C, np);
    }
    k_out<<<1, 256, 0, stream>>>(H, C, (float*)d_out);
}

// Round 7
// 699.167 us; speedup vs baseline: 1.0026x; 1.0026x over previous
//
#include <hip/hip_runtime.h>
#include <hip/hip_bf16.h>

// ChildSumTreeLSTM, fp32 in/out, depth=17, N=2^18-1, D_IN=H=128.
// R7: rcp-based sigm/tanh.
// R11: k_lvl (task = 32 parents x 16 cols, waves split K=32, LDS reduce,
//      wave0 epilogue) -> latency-optimal for SMALL levels.
// R12: k_leaf = pure throughput x@W GEMM for leaves (h bf16 / c fp32 to HBM).
// R13: R6 profile showed k_lvl at l=16 is BW-bound on 8x redundant staging
//      (FETCH 328 MB, 207 us). k_lvlb (big levels, np>=8192): stage XA/CH
//      ONCE per 32-parent block, hoist A-fragments to registers, loop the 8
//      col-tiles {weight loads + MFMA -> PR reduce -> wave0 epilogue}.
//      Barrier placement overlaps wave0's epilogue(ct) with other waves'
//      MFMAs(ct+1). Traffic at l=16: 386 -> ~184 MB.
// Weights: W plain bf16, U split-2 hi/lo bf16 (pre-swizzled to B-frag order).
// h global bf16, c global fp32. Shifted rows: row = node+1.

typedef __bf16 bf16_t;
typedef __bf16 bf16x8 __attribute__((ext_vector_type(8)));
typedef float  f32x4  __attribute__((ext_vector_type(4)));

#define MFMA16(a, b, c) __builtin_amdgcn_mfma_f32_16x16x32_bf16((a), (b), (c), 0, 0, 0)

__device__ __forceinline__ float rcp_(float x) { return __builtin_amdgcn_rcpf(x); }
// bf16-rounded outputs: 1-ulp v_rcp_f32 error is invisible.
__device__ __forceinline__ float sigm(float x) { return rcp_(1.0f + __expf(-x)); }
__device__ __forceinline__ float tanh_(float x) {
    float a = fabsf(x);
    float e = __expf(2.0f * a);
    float t = fmaf(-2.0f, rcp_(e + 1.0f), 1.0f);
    return copysignf(t, x);
}

__device__ __forceinline__ void cvt16(const float* __restrict__ src, bf16_t* __restrict__ dst)
{
    float tmp[16];
    *(float4*)&tmp[0]  = ((const float4*)src)[0];
    *(float4*)&tmp[4]  = ((const float4*)src)[1];
    *(float4*)&tmp[8]  = ((const float4*)src)[2];
    *(float4*)&tmp[12] = ((const float4*)src)[3];
    bf16_t b[16];
#pragma unroll
    for (int j = 0; j < 16; j++) b[j] = (bf16_t)tmp[j];
    *(bf16x8*)&dst[0] = *(bf16x8*)&b[0];
    *(bf16x8*)&dst[8] = *(bf16x8*)&b[8];
}

__device__ __forceinline__ void zero16(bf16_t* __restrict__ dst)
{
    bf16x8 z = (bf16x8)(bf16_t)0.f;
    *(bf16x8*)&dst[0] = z;
    *(bf16x8*)&dst[8] = z;
}

// SW layout (bf16 elems): W g (0=Wi 1=Wf 2=Wo 3=Wu) at g*16384, plain.
// U u (0=Ui 1=Uf 2=Uo 3=Uu) at 65536 + u*32768 (hi), +16384 (lo).
// idx = ((nt*4+kb)*64 + lane)*8 + j ; elem = M[kb*32+(lane>>4)*8+j][nt*16+(lane&15)]
__global__ __launch_bounds__(256)
void k_prep(const float* __restrict__ Wi, const float* __restrict__ Wf,
            const float* __restrict__ Wo, const float* __restrict__ Wu,
            const float* __restrict__ Ui, const float* __restrict__ Uf,
            const float* __restrict__ Uo, const float* __restrict__ Uu,
            bf16_t* __restrict__ SW)
{
    int b = blockIdx.x;
    const float* src;
    switch (b) {
        case 0: src = Wi; break; case 1: src = Wf; break;
        case 2: src = Wo; break; case 3: src = Wu; break;
        case 4: src = Ui; break; case 5: src = Uf; break;
        case 6: src = Uo; break; default: src = Uu; break;
    }
    if (b < 4) {
        bf16_t* hi = SW + (size_t)b * 16384;
        for (int idx = threadIdx.x; idx < 16384; idx += 256) {
            int j = idx & 7, ln = (idx >> 3) & 63, kb = (idx >> 9) & 3, nt = idx >> 11;
            int k = kb * 32 + (ln >> 4) * 8 + j;
            int n = nt * 16 + (ln & 15);
            hi[idx] = (bf16_t)src[k * 128 + n];
        }
    } else {
        bf16_t* hi = SW + 65536 + (size_t)(b - 4) * 32768;
        bf16_t* lo = hi + 16384;
        for (int idx = threadIdx.x; idx < 16384; idx += 256) {
            int j = idx & 7, ln = (idx >> 3) & 63, kb = (idx >> 9) & 3, nt = idx >> 11;
            int k = kb * 32 + (ln >> 4) * 8 + j;
            int n = nt * 16 + (ln & 15);
            float w = src[k * 128 + n];
            bf16_t hh = (bf16_t)w;
            hi[idx] = hh;
            lo[idx] = (bf16_t)(w - (float)hh);
        }
    }
}

// ---------------------------------------------------------------------------
// k_leaf: pure throughput x@W GEMM for the leaf level (np = 2^depth nodes).
// Block = 32 rows x 128 cols, 4 waves x 2 col-tiles, 3 gates (i,o,u).
__global__ __launch_bounds__(256, 4)
void k_leaf(const float* __restrict__ x, const bf16_t* __restrict__ SW,
            const float* __restrict__ bi, const float* __restrict__ bo,
            const float* __restrict__ bu,
            bf16_t* __restrict__ H, float* __restrict__ C, int np)
{
    __shared__ __align__(16) char smem[34816];
    bf16_t (*XA)[136] = (bf16_t(*)[136])smem;           //  8704
    bf16_t (*Hd)[136] = (bf16_t(*)[136])(smem + 8704);  //  8704
    float  (*Cd)[136] = (float(*)[136])(smem + 17408);  // 17408

    const int tid = threadIdx.x;
    const int srow = np + 32 * blockIdx.x;   // shifted global row base
    {
        int r = tid >> 3, cb = (tid & 7) * 16;
        cvt16(x + (size_t)(srow - 1 + r) * 128 + cb, &XA[r][cb]);
    }
    __syncthreads();
    const int wave = tid >> 6, lane = tid & 63;
    const int quad = lane >> 4, lc = lane & 15;

    f32x4 aI[2][2], aO[2][2], aU[2][2];
#pragma unroll
    for (int nt = 0; nt < 2; nt++)
#pragma unroll
        for (int mt = 0; mt < 2; mt++) {
            aI[nt][mt] = (f32x4){0.f, 0.f, 0.f, 0.f};
            aO[nt][mt] = (f32x4){0.f, 0.f, 0.f, 0.f};
            aU[nt][mt] = (f32x4){0.f, 0.f, 0.f, 0.f};
        }
#pragma unroll
    for (int kb = 0; kb < 4; kb++) {
        const int k0 = kb * 32 + quad * 8;
        bf16x8 a0 = *(const bf16x8*)&XA[lc][k0];
        bf16x8 a1 = *(const bf16x8*)&XA[16 + lc][k0];
#pragma unroll
        for (int nt = 0; nt < 2; nt++) {
            const size_t boff = ((size_t)((2 * wave + nt) * 4 + kb) * 64 + lane) * 8;
            bf16x8 bWi = *(const bf16x8*)(SW + boff);
            bf16x8 bWo = *(const bf16x8*)(SW + 32768 + boff);
            bf16x8 bWu = *(const bf16x8*)(SW + 49152 + boff);
            aI[nt][0] = MFMA16(a0, bWi, aI[nt][0]);
            aI[nt][1] = MFMA16(a1, bWi, aI[nt][1]);
            aO[nt][0] = MFMA16(a0, bWo, aO[nt][0]);
            aO[nt][1] = MFMA16(a1, bWo, aO[nt][1]);
            aU[nt][0] = MFMA16(a0, bWu, aU[nt][0]);
            aU[nt][1] = MFMA16(a1, bWu, aU[nt][1]);
        }
    }
    __syncthreads();
#pragma unroll
    for (int nt = 0; nt < 2; nt++) {
        const int col = (2 * wave + nt) * 16 + lc;
        float bii = bi[col], boi = bo[col], bui = bu[col];
#pragma unroll
        for (int mt = 0; mt < 2; mt++)
#pragma unroll
            for (int r = 0; r < 4; r++) {
                float iv = sigm(aI[nt][mt][r] + bii);
                float ov = sigm(aO[nt][mt][r] + boi);
                float uv = tanh_(aU[nt][mt][r] + bui);
                float cv = iv * uv;
                int pl = mt * 16 + quad * 4 + r;
                Hd[pl][col] = (bf16_t)(ov * tanh_(cv));
                Cd[pl][col] = cv;
            }
    }
    __syncthreads();
    {
        int r = tid >> 3, cb = (tid & 7) * 16;
        uint4* dh = (uint4*)(H + (size_t)(srow + r) * 128 + cb);
        dh[0] = *(uint4*)&Hd[r][cb];
        dh[1] = *(uint4*)&Hd[r][cb + 8];
        float4* dc = (float4*)(C + (size_t)(srow + r) * 128 + cb);
        const float4* sc4 = (const float4*)&Cd[r][cb];
        dc[0] = sc4[0]; dc[1] = sc4[1]; dc[2] = sc4[2]; dc[3] = sc4[3];
    }
}

// ---------------------------------------------------------------------------
// Shared epilogue piece: wave-0 reduce + LSTM update for one 16-col tile.
// (macro-free duplication kept inline in both kernels for clarity)

// k_lvl: small levels. Task/block = (mt, ct): 32 parents x 16 cols. Waves
// split K (wave = one K=32 slice), partials reduced via LDS, wave0 epilogue.
// LDS: PR[12][4][64] f32x4 @0 (49152) | XA[32][136] @49152 | CH[64][136]
// @57856 | SC[32][17] f32 aliases PR head. (Unchanged from R11 — verified.)
__global__ __launch_bounds__(256, 2)
void k_lvl(const float* __restrict__ x, const bf16_t* __restrict__ SW,
           const float* __restrict__ bi, const float* __restrict__ bf_,
           const float* __restrict__ bo, const float* __restrict__ bu,
           bf16_t* H, float* C, int np)
{
    __shared__ __align__(16) char smem[75264];
    f32x4  (*PR)[4][64] = (f32x4(*)[4][64])smem;
    bf16_t (*XA)[136]   = (bf16_t(*)[136])(smem + 49152);
    bf16_t (*CH)[136]   = (bf16_t(*)[136])(smem + 57856);
    float  (*SC)[17]    = (float(*)[17])smem;

    const int tid = threadIdx.x;
    const int wave = tid >> 6, lane = tid & 63;
    const int quad = lane >> 4, lc = lane & 15;

    const int task = blockIdx.x;
    const int ct = task & 7, mt = task >> 3;
    int valid = np - 32 * mt; if (valid > 32) valid = 32;
    if (valid <= 0) return;
    const int prow = np + 32 * mt;
    const int crow = 2 * np + 64 * mt;

    {   // stage XA
        int r = tid >> 3, cb = (tid & 7) * 16;
        if (r < valid) cvt16(x + (size_t)(prow - 1 + r) * 128 + cb, &XA[r][cb]);
        else           zero16(&XA[r][cb]);
    }
    {   // stage CH
        int r = tid >> 2, cb = (tid & 3) * 32;
        if (r < 2 * valid) {
            const uint4* src = (const uint4*)(H + (size_t)(crow + r) * 128 + cb);
            *(uint4*)&CH[r][cb]      = src[0];
            *(uint4*)&CH[r][cb + 8]  = src[1];
            *(uint4*)&CH[r][cb + 16] = src[2];
            *(uint4*)&CH[r][cb + 24] = src[3];
        } else {
            uint4 z = {0u, 0u, 0u, 0u};
            *(uint4*)&CH[r][cb]      = z;
            *(uint4*)&CH[r][cb + 8]  = z;
            *(uint4*)&CH[r][cb + 16] = z;
            *(uint4*)&CH[r][cb + 24] = z;
        }
    }
    __syncthreads();

    f32x4 z4 = (f32x4){0.f, 0.f, 0.f, 0.f};
    f32x4 aI0 = z4, aI1 = z4, aXf0 = z4, aXf1 = z4;
    f32x4 aO0 = z4, aO1 = z4, aU0 = z4, aU1 = z4;
    f32x4 aF0 = z4, aF1 = z4, aF2 = z4, aF3 = z4;
    {
        const int k0 = wave * 32 + quad * 8;
        bf16x8 xa0 = *(const bf16x8*)&XA[lc][k0];
        bf16x8 xa1 = *(const bf16x8*)&XA[16 + lc][k0];
        bf16x8 h00 = *(const bf16x8*)&CH[2 * lc][k0];
        bf16x8 h01 = *(const bf16x8*)&CH[2 * lc + 1][k0];
        bf16x8 h10 = *(const bf16x8*)&CH[2 * lc + 32][k0];
        bf16x8 h11 = *(const bf16x8*)&CH[2 * lc + 33][k0];
        bf16x8 at0, at1;
#pragma unroll
        for (int j = 0; j < 8; j++) {
            at0[j] = (bf16_t)((float)h00[j] + (float)h01[j]);
            at1[j] = (bf16_t)((float)h10[j] + (float)h11[j]);
        }
        bf16x8 ac0 = *(const bf16x8*)&CH[lc][k0];
        bf16x8 ac1 = *(const bf16x8*)&CH[16 + lc][k0];
        bf16x8 ac2 = *(const bf16x8*)&CH[32 + lc][k0];
        bf16x8 ac3 = *(const bf16x8*)&CH[48 + lc][k0];

        const size_t boff = ((size_t)(ct * 4 + wave) * 64 + lane) * 8;
        bf16x8 bWi = *(const bf16x8*)(SW + boff);
        bf16x8 bWf = *(const bf16x8*)(SW + 16384 + boff);
        bf16x8 bWo = *(const bf16x8*)(SW + 32768 + boff);
        bf16x8 bWu = *(const bf16x8*)(SW + 49152 + boff);
        const bf16_t* Ub = SW + 65536;
        bf16x8 bIh = *(const bf16x8*)(Ub + boff);
        bf16x8 bIl = *(const bf16x8*)(Ub + 16384 + boff);
        bf16x8 bFh = *(const bf16x8*)(Ub + 32768 + boff);
        bf16x8 bFl = *(const bf16x8*)(Ub + 49152 + boff);
        bf16x8 bOh = *(const bf16x8*)(Ub + 65536 + boff);
        bf16x8 bOl = *(const bf16x8*)(Ub + 81920 + boff);
        bf16x8 bUh = *(const bf16x8*)(Ub + 98304 + boff);
        bf16x8 bUl = *(const bf16x8*)(Ub + 114688 + boff);

        aI0  = MFMA16(xa0, bWi, aI0);  aI1  = MFMA16(xa1, bWi, aI1);
        aXf0 = MFMA16(xa0, bWf, aXf0); aXf1 = MFMA16(xa1, bWf, aXf1);
        aO0  = MFMA16(xa0, bWo, aO0);  aO1  = MFMA16(xa1, bWo, aO1);
        aU0  = MFMA16(xa0, bWu, aU0);  aU1  = MFMA16(xa1, bWu, aU1);
        aI0 = MFMA16(at0, bIh, aI0); aI0 = MFMA16(at0, bIl, aI0);
        aI1 = MFMA16(at1, bIh, aI1); aI1 = MFMA16(at1, bIl, aI1);
        aO0 = MFMA16(at0, bOh, aO0); aO0 = MFMA16(at0, bOl, aO0);
        aO1 = MFMA16(at1, bOh, aO1); aO1 = MFMA16(at1, bOl, aO1);
        aU0 = MFMA16(at0, bUh, aU0); aU0 = MFMA16(at0, bUl, aU0);
        aU1 = MFMA16(at1, bUh, aU1); aU1 = MFMA16(at1, bUl, aU1);
        aF0 = MFMA16(ac0, bFh, aF0); aF0 = MFMA16(ac0, bFl, aF0);
        aF1 = MFMA16(ac1, bFh, aF1); aF1 = MFMA16(ac1, bFl, aF1);
        aF2 = MFMA16(ac2, bFh, aF2); aF2 = MFMA16(ac2, bFl, aF2);
        aF3 = MFMA16(ac3, bFh, aF3); aF3 = MFMA16(ac3, bFl, aF3);
    }
    if (wave != 0) {
        PR[0][wave][lane]  = aI0;  PR[1][wave][lane]  = aI1;
        PR[2][wave][lane]  = aXf0; PR[3][wave][lane]  = aXf1;
        PR[4][wave][lane]  = aO0;  PR[5][wave][lane]  = aO1;
        PR[6][wave][lane]  = aU0;  PR[7][wave][lane]  = aU1;
        PR[8][wave][lane]  = aF0;  PR[9][wave][lane]  = aF1;
        PR[10][wave][lane] = aF2;  PR[11][wave][lane] = aF3;
    }
    __syncthreads();
    if (wave == 0) {
        aI0  += PR[0][1][lane]  + PR[0][2][lane]  + PR[0][3][lane];
        aI1  += PR[1][1][lane]  + PR[1][2][lane]  + PR[1][3][lane];
        aXf0 += PR[2][1][lane]  + PR[2][2][lane]  + PR[2][3][lane];
        aXf1 += PR[3][1][lane]  + PR[3][2][lane]  + PR[3][3][lane];
        aO0  += PR[4][1][lane]  + PR[4][2][lane]  + PR[4][3][lane];
        aO1  += PR[5][1][lane]  + PR[5][2][lane]  + PR[5][3][lane];
        aU0  += PR[6][1][lane]  + PR[6][2][lane]  + PR[6][3][lane];
        aU1  += PR[7][1][lane]  + PR[7][2][lane]  + PR[7][3][lane];
        aF0  += PR[8][1][lane]  + PR[8][2][lane]  + PR[8][3][lane];
        aF1  += PR[9][1][lane]  + PR[9][2][lane]  + PR[9][3][lane];
        aF2  += PR[10][1][lane] + PR[10][2][lane] + PR[10][3][lane];
        aF3  += PR[11][1][lane] + PR[11][2][lane] + PR[11][3][lane];

        const int colg = ct * 16 + lc;
        float c0v[4][2], c1v[4][2];
#pragma unroll
        for (int m2 = 0; m2 < 4; m2++)
#pragma unroll
            for (int pi = 0; pi < 2; pi++) {
                int pl = m2 * 8 + quad * 2 + pi;
                size_t cr = (size_t)(crow + 2 * pl) * 128 + colg;
                c0v[m2][pi] = C[cr];
                c1v[m2][pi] = C[cr + 128];
            }
        float bfv = bf_[colg];
#pragma unroll
        for (int r = 0; r < 4; r++) {
            SC[quad * 4 + r][lc]      = aXf0[r] + bfv;
            SC[16 + quad * 4 + r][lc] = aXf1[r] + bfv;
        }
#define NS_FPATH(M2, AF)                                            \
        _Pragma("unroll")                                           \
        for (int pi = 0; pi < 2; pi++) {                            \
            int pl = M2 * 8 + quad * 2 + pi;                        \
            float xf = SC[pl][lc];                                  \
            float f0 = sigm(xf + AF[2 * pi]);                       \
            float f1 = sigm(xf + AF[2 * pi + 1]);                   \
            SC[pl][lc] = f0 * c0v[M2][pi] + f1 * c1v[M2][pi];       \
        }
        NS_FPATH(0, aF0) NS_FPATH(1, aF1) NS_FPATH(2, aF2) NS_FPATH(3, aF3)
#undef NS_FPATH
        float bii = bi[colg], boi = bo[colg], bui = bu[colg];
#define NS_IOU(MT, AI, AO, AU)                                      \
        _Pragma("unroll")                                           \
        for (int r = 0; r < 4; r++) {                               \
            int pl = MT * 16 + quad * 4 + r;                        \
            float iv = sigm(AI[r] + bii);                           \
            float ov = sigm(AO[r] + boi);                           \
            float uv = tanh_(AU[r] + bui);                          \
            float cv = iv * uv + SC[pl][lc];                        \
            if (pl < valid) {                                       \
                H[(size_t)(prow + pl) * 128 + colg] = (bf16_t)(ov * tanh_(cv)); \
                C[(size_t)(prow + pl) * 128 + colg] = cv;           \
            }                                                       \
        }
        NS_IOU(0, aI0, aO0, aU0)
        NS_IOU(1, aI1, aO1, aU1)
#undef NS_IOU
    }
}

// ---------------------------------------------------------------------------
// k_lvlb: BIG levels (np multiple of 32, np >= 8192 -> valid always 32).
// Block = 32 parents x ALL 128 cols. Stage XA/CH once, hoist A-fragments to
// registers, loop 8 col-tiles: {12 weight loads + 28 MFMA} -> PR -> wave0
// epilogue. Epilogue(ct) overlaps other waves' MFMAs(ct+1) via barrier order.
__global__ __launch_bounds__(256, 2)
void k_lvlb(const float* __restrict__ x, const bf16_t* __restrict__ SW,
            const float* __restrict__ bi, const float* __restrict__ bf_,
            const float* __restrict__ bo, const float* __restrict__ bu,
            bf16_t* H, float* C, int np)
{
    __shared__ __align__(16) char smem[75264];
    f32x4  (*PR)[4][64] = (f32x4(*)[4][64])smem;
    bf16_t (*XA)[136]   = (bf16_t(*)[136])(smem + 49152);
    bf16_t (*CH)[136]   = (bf16_t(*)[136])(smem + 57856);
    float  (*SC)[17]    = (float(*)[17])smem;

    const int tid = threadIdx.x;
    const int wave = tid >> 6, lane = tid & 63;
    const int quad = lane >> 4, lc = lane & 15;

    const int t = blockIdx.x;
    const int prow = np + 32 * t;
    const int crow = 2 * np + 64 * t;

    {   // stage XA (always full 32 rows)
        int r = tid >> 3, cb = (tid & 7) * 16;
        cvt16(x + (size_t)(prow - 1 + r) * 128 + cb, &XA[r][cb]);
    }
    {   // stage CH (full 64 rows)
        int r = tid >> 2, cb = (tid & 3) * 32;
        const uint4* src = (const uint4*)(H + (size_t)(crow + r) * 128 + cb);
        *(uint4*)&CH[r][cb]      = src[0];
        *(uint4*)&CH[r][cb + 8]  = src[1];
        *(uint4*)&CH[r][cb + 16] = src[2];
        *(uint4*)&CH[r][cb + 24] = src[3];
    }
    __syncthreads();

    // loop-invariant A-fragments (10 x bf16x8 = 40 VGPRs)
    const int k0 = wave * 32 + quad * 8;
    bf16x8 xa0 = *(const bf16x8*)&XA[lc][k0];
    bf16x8 xa1 = *(const bf16x8*)&XA[16 + lc][k0];
    bf16x8 at0, at1;
    {
        bf16x8 h00 = *(const bf16x8*)&CH[2 * lc][k0];
        bf16x8 h01 = *(const bf16x8*)&CH[2 * lc + 1][k0];
        bf16x8 h10 = *(const bf16x8*)&CH[2 * lc + 32][k0];
        bf16x8 h11 = *(const bf16x8*)&CH[2 * lc + 33][k0];
#pragma unroll
        for (int j = 0; j < 8; j++) {
            at0[j] = (bf16_t)((float)h00[j] + (float)h01[j]);
            at1[j] = (bf16_t)((float)h10[j] + (float)h11[j]);
        }
    }
    bf16x8 ac0 = *(const bf16x8*)&CH[lc][k0];
    bf16x8 ac1 = *(const bf16x8*)&CH[16 + lc][k0];
    bf16x8 ac2 = *(const bf16x8*)&CH[32 + lc][k0];
    bf16x8 ac3 = *(const bf16x8*)&CH[48 + lc][k0];

    for (int ct = 0; ct < 8; ct++) {
        f32x4 z4 = (f32x4){0.f, 0.f, 0.f, 0.f};
        f32x4 aI0 = z4, aI1 = z4, aXf0 = z4, aXf1 = z4;
        f32x4 aO0 = z4, aO1 = z4, aU0 = z4, aU1 = z4;
        f32x4 aF0 = z4, aF1 = z4, aF2 = z4, aF3 = z4;
        {
            const size_t boff = ((size_t)(ct * 4 + wave) * 64 + lane) * 8;
            bf16x8 bWi = *(const bf16x8*)(SW + boff);
            bf16x8 bWf = *(const bf16x8*)(SW + 16384 + boff);
            bf16x8 bWo = *(const bf16x8*)(SW + 32768 + boff);
            bf16x8 bWu = *(const bf16x8*)(SW + 49152 + boff);
            const bf16_t* Ub = SW + 65536;
            bf16x8 bIh = *(const bf16x8*)(Ub + boff);
            bf16x8 bIl = *(const bf16x8*)(Ub + 16384 + boff);
            bf16x8 bFh = *(const bf16x8*)(Ub + 32768 + boff);
            bf16x8 bFl = *(const bf16x8*)(Ub + 49152 + boff);
            bf16x8 bOh = *(const bf16x8*)(Ub + 65536 + boff);
            bf16x8 bOl = *(const bf16x8*)(Ub + 81920 + boff);
            bf16x8 bUh = *(const bf16x8*)(Ub + 98304 + boff);
            bf16x8 bUl = *(const bf16x8*)(Ub + 114688 + boff);

            aI0  = MFMA16(xa0, bWi, aI0);  aI1  = MFMA16(xa1, bWi, aI1);
            aXf0 = MFMA16(xa0, bWf, aXf0); aXf1 = MFMA16(xa1, bWf, aXf1);
            aO0  = MFMA16(xa0, bWo, aO0);  aO1  = MFMA16(xa1, bWo, aO1);
            aU0  = MFMA16(xa0, bWu, aU0);  aU1  = MFMA16(xa1, bWu, aU1);
            aI0 = MFMA16(at0, bIh, aI0); aI0 = MFMA16(at0, bIl, aI0);
            aI1 = MFMA16(at1, bIh, aI1); aI1 = MFMA16(at1, bIl, aI1);
            aO0 = MFMA16(at0, bOh, aO0); aO0 = MFMA16(at0, bOl, aO0);
            aO1 = MFMA16(at1, bOh, aO1); aO1 = MFMA16(at1, bOl, aO1);
            aU0 = MFMA16(at0, bUh, aU0); aU0 = MFMA16(at0, bUl, aU0);
            aU1 = MFMA16(at1, bUh, aU1); aU1 = MFMA16(at1, bUl, aU1);
            aF0 = MFMA16(ac0, bFh, aF0); aF0 = MFMA16(ac0, bFl, aF0);
            aF1 = MFMA16(ac1, bFh, aF1); aF1 = MFMA16(ac1, bFl, aF1);
            aF2 = MFMA16(ac2, bFh, aF2); aF2 = MFMA16(ac2, bFl, aF2);
            aF3 = MFMA16(ac3, bFh, aF3); aF3 = MFMA16(ac3, bFl, aF3);
        }
        __syncthreads();   // A: previous ct's PR reads (wave0 reduce) are done
        if (wave != 0) {
            PR[0][wave][lane]  = aI0;  PR[1][wave][lane]  = aI1;
            PR[2][wave][lane]  = aXf0; PR[3][wave][lane]  = aXf1;
            PR[4][wave][lane]  = aO0;  PR[5][wave][lane]  = aO1;
            PR[6][wave][lane]  = aU0;  PR[7][wave][lane]  = aU1;
            PR[8][wave][lane]  = aF0;  PR[9][wave][lane]  = aF1;
            PR[10][wave][lane] = aF2;  PR[11][wave][lane] = aF3;
        }
        __syncthreads();   // B: PR complete; other waves run ahead into ct+1
        if (wave == 0) {
            aI0  += PR[0][1][lane]  + PR[0][2][lane]  + PR[0][3][lane];
            aI1  += PR[1][1][lane]  + PR[1][2][lane]  + PR[1][3][lane];
            aXf0 += PR[2][1][lane]  + PR[2][2][lane]  + PR[2][3][lane];
            aXf1 += PR[3][1][lane]  + PR[3][2][lane]  + PR[3][3][lane];
            aO0  += PR[4][1][lane]  + PR[4][2][lane]  + PR[4][3][lane];
            aO1  += PR[5][1][lane]  + PR[5][2][lane]  + PR[5][3][lane];
            aU0  += PR[6][1][lane]  + PR[6][2][lane]  + PR[6][3][lane];
            aU1  += PR[7][1][lane]  + PR[7][2][lane]  + PR[7][3][lane];
            aF0  += PR[8][1][lane]  + PR[8][2][lane]  + PR[8][3][lane];
            aF1  += PR[9][1][lane]  + PR[9][2][lane]  + PR[9][3][lane];
            aF2  += PR[10][1][lane] + PR[10][2][lane] + PR[10][3][lane];
            aF3  += PR[11][1][lane] + PR[11][2][lane] + PR[11][3][lane];

            const int colg = ct * 16 + lc;
            float c0v[4][2], c1v[4][2];
#pragma unroll
            for (int m2 = 0; m2 < 4; m2++)
#pragma unroll
                for (int pi = 0; pi < 2; pi++) {
                    int pl = m2 * 8 + quad * 2 + pi;
                    size_t cr = (size_t)(crow + 2 * pl) * 128 + colg;
                    c0v[m2][pi] = C[cr];
                    c1v[m2][pi] = C[cr + 128];
                }
            // xf exchange via in-wave shuffle-free LDS slice of SC (PR head
            // is free for wave0: its own partials never went to LDS). SC is
            // wave-0 private; reads/writes are in-wave RAW (lockstep-safe).
            float bfv = bf_[colg];
#pragma unroll
            for (int r = 0; r < 4; r++) {
                SC[quad * 4 + r][lc]      = aXf0[r] + bfv;
                SC[16 + quad * 4 + r][lc] = aXf1[r] + bfv;
            }
#define NS_FPATH(M2, AF)                                            \
            _Pragma("unroll")                                       \
            for (int pi = 0; pi < 2; pi++) {                        \
                int pl = M2 * 8 + quad * 2 + pi;                    \
                float xf = SC[pl][lc];                              \
                float f0 = sigm(xf + AF[2 * pi]);                   \
                float f1 = sigm(xf + AF[2 * pi + 1]);               \
                SC[pl][lc] = f0 * c0v[M2][pi] + f1 * c1v[M2][pi];   \
            }
            NS_FPATH(0, aF0) NS_FPATH(1, aF1) NS_FPATH(2, aF2) NS_FPATH(3, aF3)
#undef NS_FPATH
            float bii = bi[colg], boi = bo[colg], bui = bu[colg];
#define NS_IOU(MT, AI, AO, AU)                                      \
            _Pragma("unroll")                                       \
            for (int r = 0; r < 4; r++) {                           \
                int pl = MT * 16 + quad * 4 + r;                    \
                float iv = sigm(AI[r] + bii);                       \
                float ov = sigm(AO[r] + boi);                       \
                float uv = tanh_(AU[r] + bui);                      \
                float cv = iv * uv + SC[pl][lc];                    \
                H[(size_t)(prow + pl) * 128 + colg] = (bf16_t)(ov * tanh_(cv)); \
                C[(size_t)(prow + pl) * 128 + colg] = cv;           \
            }
            NS_IOU(0, aI0, aO0, aU0)
            NS_IOU(1, aI1, aO1, aU1)
#undef NS_IOU
        }
    }
    // NOTE: wave0's SC region (PR head) is only touched by wave0 between
    // barriers A/B of consecutive iterations; PR[*][1..3] slots used by other
    // waves start at f32x4 index >= 64, disjoint from SC[32][17] (2176 B).
}

__global__ __launch_bounds__(256)
void k_out(const bf16_t* __restrict__ H, const float* __restrict__ C,
           float* __restrict__ out)
{
    int t = threadIdx.x;
    if (t < 128)      out[t] = (float)H[128 + t];   // shifted row 1 = root
    else if (t < 256) out[t] = C[t];                // C[128 + (t-128)]
}

// ---------------------------------------------------------------------------
extern "C" void kernel_launch(void* const* d_in, const int* in_sizes, int n_in,
                              void* d_out, int out_size, void* d_ws, size_t ws_size,
                              hipStream_t stream)
{
    const float* x   = (const float*)d_in[0];
    const float* Wi  = (const float*)d_in[1];
    const float* bi  = (const float*)d_in[2];
    const float* Ui  = (const float*)d_in[3];
    const float* Wf  = (const float*)d_in[4];
    const float* bf_ = (const float*)d_in[5];
    const float* Uf  = (const float*)d_in[6];
    const float* Wo  = (const float*)d_in[7];
    const float* bo  = (const float*)d_in[8];
    const float* Uo  = (const float*)d_in[9];
    const float* Wu  = (const float*)d_in[10];
    const float* bu  = (const float*)d_in[11];
    const float* Uu  = (const float*)d_in[12];

    int Ntot  = in_sizes[0] / 128;
    int depth = 31 - __builtin_clz((unsigned)(Ntot + 1)) - 1;

    // workspace: SW 384 KB | H bf16 (Ntot+1)*128 | C fp32 (Ntot+1)*128
    char* w = (char*)d_ws;
    bf16_t* SW = (bf16_t*)w;  w += 393216;
    bf16_t* H  = (bf16_t*)w;  w += (size_t)(Ntot + 1) * 128 * sizeof(bf16_t);
    float*  C  = (float*)w;

    k_prep<<<8, 256, 0, stream>>>(Wi, Wf, Wo, Wu, Ui, Uf, Uo, Uu, SW);

    // leaves: pure x@W throughput GEMM -> global h/c
    int NL = 1 << depth;
    k_leaf<<<NL / 32, 256, 0, stream>>>(x, SW, bi, bo, bu, H, C, NL);

    // internal levels
    for (int l = depth - 1; l >= 0; l--) {
        int np = 1 << l;
        if (np >= 8192) {
            k_lvlb<<<np / 32, 256, 0, stream>>>(x, SW, bi, bf_, bo, bu, H, C, np);
        } else {
            int nmt = (np + 31) / 32;
            k_lvl<<<nmt * 8, 256, 0, stream>>>(x, SW, bi, bf_, bo, bu, H, C, np);
        }
    }
    k_out<<<1, 256, 0, stream>>>(H, C, (float*)d_out);
}

// Round 8
// 527.743 us; speedup vs baseline: 1.3283x; 1.3248x over previous
//
#include <hip/hip_runtime.h>
#include <hip/hip_bf16.h>

// ChildSumTreeLSTM, fp32 in/out, depth=17, N=2^18-1, D_IN=H=128.
// R7: rcp-based sigm/tanh.
// R11 (=R5 bench, 511 us, BEST): k_pair leaf (L17+16 fused in LDS) + k_pair
//      A=14 (L15+14) + k_lvl per level 13..0 (task = 32 parents x 16 cols,
//      waves split K=32, LDS reduce, wave0 epilogue).
// R12/R13 (REVERTED): standalone big-level kernels (k_leaf+k_lvlb) are
//      per-block latency-bound at ~50 us/block-round regardless of traffic;
//      pair fusion is 4x better per node (no mid-level HBM round trip).
// R14: leaf-specialized k_pairleaf — the 64-row HC staging buffer is unused
//      for leaf blocks (only its 32-row Hd alias). LDS 60928 -> 52224 B
//      => 3 blocks/CU (was 2): +50% resident waves on the latency-bound
//      top dispatch (155 us, 4 rounds -> 2.7 rounds).
// Weights: W plain bf16, U split-2 hi/lo bf16 (pre-swizzled to B-frag order).
// h global bf16, c global fp32. Shifted rows: row = node+1.

typedef __bf16 bf16_t;
typedef __bf16 bf16x8 __attribute__((ext_vector_type(8)));
typedef float  f32x4  __attribute__((ext_vector_type(4)));

#define MFMA16(a, b, c) __builtin_amdgcn_mfma_f32_16x16x32_bf16((a), (b), (c), 0, 0, 0)

__device__ __forceinline__ float rcp_(float x) { return __builtin_amdgcn_rcpf(x); }
// bf16-rounded outputs: 1-ulp v_rcp_f32 error is invisible.
__device__ __forceinline__ float sigm(float x) { return rcp_(1.0f + __expf(-x)); }
__device__ __forceinline__ float tanh_(float x) {
    float a = fabsf(x);
    float e = __expf(2.0f * a);
    float t = fmaf(-2.0f, rcp_(e + 1.0f), 1.0f);
    return copysignf(t, x);
}

__device__ __forceinline__ void cvt16(const float* __restrict__ src, bf16_t* __restrict__ dst)
{
    float tmp[16];
    *(float4*)&tmp[0]  = ((const float4*)src)[0];
    *(float4*)&tmp[4]  = ((const float4*)src)[1];
    *(float4*)&tmp[8]  = ((const float4*)src)[2];
    *(float4*)&tmp[12] = ((const float4*)src)[3];
    bf16_t b[16];
#pragma unroll
    for (int j = 0; j < 16; j++) b[j] = (bf16_t)tmp[j];
    *(bf16x8*)&dst[0] = *(bf16x8*)&b[0];
    *(bf16x8*)&dst[8] = *(bf16x8*)&b[8];
}

__device__ __forceinline__ void zero16(bf16_t* __restrict__ dst)
{
    bf16x8 z = (bf16x8)(bf16_t)0.f;
    *(bf16x8*)&dst[0] = z;
    *(bf16x8*)&dst[8] = z;
}

// SW layout (bf16 elems): W g (0=Wi 1=Wf 2=Wo 3=Wu) at g*16384, plain.
// U u (0=Ui 1=Uf 2=Uo 3=Uu) at 65536 + u*32768 (hi), +16384 (lo).
// idx = ((nt*4+kb)*64 + lane)*8 + j ; elem = M[kb*32+(lane>>4)*8+j][nt*16+(lane&15)]
__global__ __launch_bounds__(256)
void k_prep(const float* __restrict__ Wi, const float* __restrict__ Wf,
            const float* __restrict__ Wo, const float* __restrict__ Wu,
            const float* __restrict__ Ui, const float* __restrict__ Uf,
            const float* __restrict__ Uo, const float* __restrict__ Uu,
            bf16_t* __restrict__ SW)
{
    int b = blockIdx.x;
    const float* src;
    switch (b) {
        case 0: src = Wi; break; case 1: src = Wf; break;
        case 2: src = Wo; break; case 3: src = Wu; break;
        case 4: src = Ui; break; case 5: src = Uf; break;
        case 6: src = Uo; break; default: src = Uu; break;
    }
    if (b < 4) {
        bf16_t* hi = SW + (size_t)b * 16384;
        for (int idx = threadIdx.x; idx < 16384; idx += 256) {
            int j = idx & 7, ln = (idx >> 3) & 63, kb = (idx >> 9) & 3, nt = idx >> 11;
            int k = kb * 32 + (ln >> 4) * 8 + j;
            int n = nt * 16 + (ln & 15);
            hi[idx] = (bf16_t)src[k * 128 + n];
        }
    } else {
        bf16_t* hi = SW + 65536 + (size_t)(b - 4) * 32768;
        bf16_t* lo = hi + 16384;
        for (int idx = threadIdx.x; idx < 16384; idx += 256) {
            int j = idx & 7, ln = (idx >> 3) & 63, kb = (idx >> 9) & 3, nt = idx >> 11;
            int k = kb * 32 + (ln >> 4) * 8 + j;
            int n = nt * 16 + (ln & 15);
            float w = src[k * 128 + n];
            bf16_t hh = (bf16_t)w;
            hi[idx] = hh;
            lo[idx] = (bf16_t)(w - (float)hh);
        }
    }
}

// ---------------------------------------------------------------------------
// Leaves: 32 rows, 3-gate x@W, in-lane epilogue -> BH/BC (LDS, bf16).
__device__ __forceinline__ void leaf32(
    const float* __restrict__ x, const bf16_t* __restrict__ SW,
    const float* __restrict__ bi, const float* __restrict__ bo,
    const float* __restrict__ bu,
    bf16_t (* __restrict__ XA)[136],
    bf16_t (* __restrict__ BH)[136], bf16_t (* __restrict__ BC)[136],
    int xRowBase, int valid, int outRowOff, int tid)
{
    {
        int r = tid >> 3, cb = (tid & 7) * 16;
        if (r < valid) cvt16(x + (size_t)(xRowBase + r - 1) * 128 + cb, &XA[r][cb]);
        else           zero16(&XA[r][cb]);
    }
    __syncthreads();
    const int wave = tid >> 6, lane = tid & 63;
    const int quad = lane >> 4, lc = lane & 15;

    f32x4 aI[2][2], aO[2][2], aU[2][2];
#pragma unroll
    for (int nt = 0; nt < 2; nt++)
#pragma unroll
        for (int mt = 0; mt < 2; mt++) {
            aI[nt][mt] = (f32x4){0.f, 0.f, 0.f, 0.f};
            aO[nt][mt] = (f32x4){0.f, 0.f, 0.f, 0.f};
            aU[nt][mt] = (f32x4){0.f, 0.f, 0.f, 0.f};
        }
    for (int kb = 0; kb < 4; kb++) {
        const int k0 = kb * 32 + quad * 8;
        bf16x8 a0 = *(const bf16x8*)&XA[lc][k0];
        bf16x8 a1 = *(const bf16x8*)&XA[16 + lc][k0];
#pragma unroll
        for (int nt = 0; nt < 2; nt++) {
            const size_t boff = ((size_t)((2 * wave + nt) * 4 + kb) * 64 + lane) * 8;
            bf16x8 bWi = *(const bf16x8*)(SW + boff);
            bf16x8 bWo = *(const bf16x8*)(SW + 32768 + boff);
            bf16x8 bWu = *(const bf16x8*)(SW + 49152 + boff);
            aI[nt][0] = MFMA16(a0, bWi, aI[nt][0]);
            aI[nt][1] = MFMA16(a1, bWi, aI[nt][1]);
            aO[nt][0] = MFMA16(a0, bWo, aO[nt][0]);
            aO[nt][1] = MFMA16(a1, bWo, aO[nt][1]);
            aU[nt][0] = MFMA16(a0, bWu, aU[nt][0]);
            aU[nt][1] = MFMA16(a1, bWu, aU[nt][1]);
        }
    }
#pragma unroll
    for (int nt = 0; nt < 2; nt++) {
        const int col = (2 * wave + nt) * 16 + lc;
        float bii = bi[col], boi = bo[col], bui = bu[col];
#pragma unroll
        for (int mt = 0; mt < 2; mt++)
#pragma unroll
            for (int r = 0; r < 4; r++) {
                float iv = sigm(aI[nt][mt][r] + bii);
                float ov = sigm(aO[nt][mt][r] + boi);
                float uv = tanh_(aU[nt][mt][r] + bui);
                float cv = iv * uv;
                int pl = mt * 16 + quad * 4 + r;
                BH[outRowOff + pl][col] = (bf16_t)(ov * tanh_(cv));
                BC[outRowOff + pl][col] = (bf16_t)cv;
            }
    }
    __syncthreads();
}

// ---------------------------------------------------------------------------
// 32 internal nodes: x@W (4 gates) + ht@[Ui|Uo|Uu] + hc@Uf (split-2) + update.
__device__ __forceinline__ void compute32(
    const float* __restrict__ x, const bf16_t* __restrict__ SW,
    const float* __restrict__ bi, const float* __restrict__ bf_,
    const float* __restrict__ bo, const float* __restrict__ bu,
    bf16_t (* __restrict__ XA)[136], float (* __restrict__ SC)[132],
    const bf16_t (* __restrict__ CH)[136],
    const float* __restrict__ Cglob, int ccBase,
    const bf16_t (* __restrict__ BCc)[136], bool ccLds,
    int xRowBase, int valid,
    bf16_t (* __restrict__ BHo)[136], bf16_t (* __restrict__ BCo)[136], int outRowOff,
    bf16_t* __restrict__ Hg, float* __restrict__ Cg, int outBase,
    bf16_t (* __restrict__ Hd)[136], bool outLds, int tid)
{
    {
        int r = tid >> 3, cb = (tid & 7) * 16;
        if (r < valid) cvt16(x + (size_t)(xRowBase + r - 1) * 128 + cb, &XA[r][cb]);
        else           zero16(&XA[r][cb]);
    }
    __syncthreads();

    const int wave = tid >> 6, lane = tid & 63;
    const int quad = lane >> 4, lc = lane & 15;

    f32x4 aI[2][2], aO[2][2], aU[2][2], aXf[2][2], aF[2][4];
#pragma unroll
    for (int nt = 0; nt < 2; nt++) {
#pragma unroll
        for (int mt = 0; mt < 2; mt++) {
            aI[nt][mt]  = (f32x4){0.f, 0.f, 0.f, 0.f};
            aO[nt][mt]  = (f32x4){0.f, 0.f, 0.f, 0.f};
            aU[nt][mt]  = (f32x4){0.f, 0.f, 0.f, 0.f};
            aXf[nt][mt] = (f32x4){0.f, 0.f, 0.f, 0.f};
        }
#pragma unroll
        for (int mt = 0; mt < 4; mt++) aF[nt][mt] = (f32x4){0.f, 0.f, 0.f, 0.f};
    }

    for (int kb = 0; kb < 4; kb++) {
        const int k0 = kb * 32 + quad * 8;
        bf16x8 xa0 = *(const bf16x8*)&XA[lc][k0];
        bf16x8 xa1 = *(const bf16x8*)&XA[16 + lc][k0];
        bf16x8 h00 = *(const bf16x8*)&CH[2 * lc][k0];
        bf16x8 h01 = *(const bf16x8*)&CH[2 * lc + 1][k0];
        bf16x8 h10 = *(const bf16x8*)&CH[2 * lc + 32][k0];
        bf16x8 h11 = *(const bf16x8*)&CH[2 * lc + 33][k0];
        bf16x8 at0, at1;
#pragma unroll
        for (int j = 0; j < 8; j++) {
            at0[j] = (bf16_t)((float)h00[j] + (float)h01[j]);
            at1[j] = (bf16_t)((float)h10[j] + (float)h11[j]);
        }
        bf16x8 ac0 = *(const bf16x8*)&CH[lc][k0];
        bf16x8 ac1 = *(const bf16x8*)&CH[16 + lc][k0];
        bf16x8 ac2 = *(const bf16x8*)&CH[32 + lc][k0];
        bf16x8 ac3 = *(const bf16x8*)&CH[48 + lc][k0];
#pragma unroll
        for (int nt = 0; nt < 2; nt++) {
            const size_t boff = ((size_t)((2 * wave + nt) * 4 + kb) * 64 + lane) * 8;
            bf16x8 bWi = *(const bf16x8*)(SW + boff);
            bf16x8 bWf = *(const bf16x8*)(SW + 16384 + boff);
            bf16x8 bWo = *(const bf16x8*)(SW + 32768 + boff);
            bf16x8 bWu = *(const bf16x8*)(SW + 49152 + boff);
            aI[nt][0]  = MFMA16(xa0, bWi, aI[nt][0]);
            aI[nt][1]  = MFMA16(xa1, bWi, aI[nt][1]);
            aXf[nt][0] = MFMA16(xa0, bWf, aXf[nt][0]);
            aXf[nt][1] = MFMA16(xa1, bWf, aXf[nt][1]);
            aO[nt][0]  = MFMA16(xa0, bWo, aO[nt][0]);
            aO[nt][1]  = MFMA16(xa1, bWo, aO[nt][1]);
            aU[nt][0]  = MFMA16(xa0, bWu, aU[nt][0]);
            aU[nt][1]  = MFMA16(xa1, bWu, aU[nt][1]);
            const bf16_t* Ub = SW + 65536;
            bf16x8 bIh = *(const bf16x8*)(Ub + boff);
            bf16x8 bIl = *(const bf16x8*)(Ub + 16384 + boff);
            aI[nt][0] = MFMA16(at0, bIh, aI[nt][0]);
            aI[nt][0] = MFMA16(at0, bIl, aI[nt][0]);
            aI[nt][1] = MFMA16(at1, bIh, aI[nt][1]);
            aI[nt][1] = MFMA16(at1, bIl, aI[nt][1]);
            bf16x8 bOh = *(const bf16x8*)(Ub + 65536 + boff);
            bf16x8 bOl = *(const bf16x8*)(Ub + 81920 + boff);
            aO[nt][0] = MFMA16(at0, bOh, aO[nt][0]);
            aO[nt][0] = MFMA16(at0, bOl, aO[nt][0]);
            aO[nt][1] = MFMA16(at1, bOh, aO[nt][1]);
            aO[nt][1] = MFMA16(at1, bOl, aO[nt][1]);
            bf16x8 bUh = *(const bf16x8*)(Ub + 98304 + boff);
            bf16x8 bUl = *(const bf16x8*)(Ub + 114688 + boff);
            aU[nt][0] = MFMA16(at0, bUh, aU[nt][0]);
            aU[nt][0] = MFMA16(at0, bUl, aU[nt][0]);
            aU[nt][1] = MFMA16(at1, bUh, aU[nt][1]);
            aU[nt][1] = MFMA16(at1, bUl, aU[nt][1]);
            bf16x8 bFh = *(const bf16x8*)(Ub + 32768 + boff);
            bf16x8 bFl = *(const bf16x8*)(Ub + 49152 + boff);
            aF[nt][0] = MFMA16(ac0, bFh, aF[nt][0]);
            aF[nt][0] = MFMA16(ac0, bFl, aF[nt][0]);
            aF[nt][1] = MFMA16(ac1, bFh, aF[nt][1]);
            aF[nt][1] = MFMA16(ac1, bFl, aF[nt][1]);
            aF[nt][2] = MFMA16(ac2, bFh, aF[nt][2]);
            aF[nt][2] = MFMA16(ac2, bFl, aF[nt][2]);
            aF[nt][3] = MFMA16(ac3, bFh, aF[nt][3]);
            aF[nt][3] = MFMA16(ac3, bFl, aF[nt][3]);
        }
    }
    __syncthreads();   // XA/CH-staging reads done; SC (alias) becomes writable

    // dump xf (+bias) for the f-path row exchange
#pragma unroll
    for (int nt = 0; nt < 2; nt++) {
        const int col = (2 * wave + nt) * 16 + lc;
        float bfv = bf_[col];
#pragma unroll
        for (int mt = 0; mt < 2; mt++)
#pragma unroll
            for (int r = 0; r < 4; r++)
                SC[mt * 16 + quad * 4 + r][col] = aXf[nt][mt][r] + bfv;
    }
    __syncthreads();

    // f-path: S[pl][col] = f0*c0 + f1*c1, children are in-lane reg pairs
    float Sv[2][4][2];
#pragma unroll
    for (int nt = 0; nt < 2; nt++) {
        const int col = (2 * wave + nt) * 16 + lc;
#pragma unroll
        for (int mt = 0; mt < 4; mt++)
#pragma unroll
            for (int pi = 0; pi < 2; pi++) {
                int pl = mt * 8 + quad * 2 + pi;
                float xf = SC[pl][col];
                float f0 = sigm(xf + aF[nt][mt][2 * pi]);
                float f1 = sigm(xf + aF[nt][mt][2 * pi + 1]);
                float c0, c1;
                if (ccLds) {
                    c0 = (float)BCc[2 * pl][col];
                    c1 = (float)BCc[2 * pl + 1][col];
                } else {
                    size_t cr = (size_t)(ccBase + 2 * pl) * 128 + col;
                    c0 = Cglob[cr];
                    c1 = Cglob[cr + 128];
                }
                Sv[nt][mt][pi] = f0 * c0 + f1 * c1;
            }
    }
    __syncthreads();   // all xf reads done -> SC overwritable in place
#pragma unroll
    for (int nt = 0; nt < 2; nt++) {
        const int col = (2 * wave + nt) * 16 + lc;
#pragma unroll
        for (int mt = 0; mt < 4; mt++)
#pragma unroll
            for (int pi = 0; pi < 2; pi++)
                SC[mt * 8 + quad * 2 + pi][col] = Sv[nt][mt][pi];
    }
    __syncthreads();

    // i/o/u + cell update
    float hr[2][2][4];
#pragma unroll
    for (int nt = 0; nt < 2; nt++) {
        const int col = (2 * wave + nt) * 16 + lc;
        float bii = bi[col], boi = bo[col], bui = bu[col];
#pragma unroll
        for (int mt = 0; mt < 2; mt++)
#pragma unroll
            for (int r = 0; r < 4; r++) {
                int pl = mt * 16 + quad * 4 + r;
                float iv = sigm(aI[nt][mt][r] + bii);
                float ov = sigm(aO[nt][mt][r] + boi);
                float uv = tanh_(aU[nt][mt][r] + bui);
                float cv = iv * uv + SC[pl][col];
                float hv = ov * tanh_(cv);
                hr[nt][mt][r] = hv;
                if (outLds) {
                    BHo[outRowOff + pl][col] = (bf16_t)hv;
                    BCo[outRowOff + pl][col] = (bf16_t)cv;
                } else if (pl < valid) {
                    Cg[(size_t)(outBase + pl) * 128 + col] = cv;
                }
            }
    }
    if (outLds) {
        __syncthreads();
    } else {
        __syncthreads();   // SC reads done -> Hd (overlapping region) writable
#pragma unroll
        for (int nt = 0; nt < 2; nt++) {
            const int col = (2 * wave + nt) * 16 + lc;
#pragma unroll
            for (int mt = 0; mt < 2; mt++)
#pragma unroll
                for (int r = 0; r < 4; r++)
                    Hd[mt * 16 + quad * 4 + r][col] = (bf16_t)hr[nt][mt][r];
        }
        __syncthreads();
        int r = tid >> 3, cb = (tid & 7) * 16;
        if (r < valid) {
            uint4* dst = (uint4*)(Hg + (size_t)(outBase + r) * 128 + cb);
            dst[0] = *(uint4*)&Hd[r][cb];
            dst[1] = *(uint4*)&Hd[r][cb + 8];
        }
        __syncthreads();
    }
}

// ---------------------------------------------------------------------------
// k_pairleaf: block = 32 level-A parents, B = leaves. HC staging is unused
// for leaf blocks, so Hd gets its own 32-row buffer: LDS 52224 B -> 3
// blocks/CU (vs 2 for the generic k_pair). Level sizes are exact multiples
// of 32 here (np >= 2^14), so no valid/zero handling needed.
// LDS: XA[32][136] @0 | Hd[32][136] @8704 | BH[64][136] @17408 |
//      BC[64][136] @34816 | SC[32][132] f32 @0 (alias XA+Hd, post-K only).
__global__ __launch_bounds__(256, 3)
void k_pairleaf(const float* __restrict__ x, const bf16_t* __restrict__ SW,
                const float* __restrict__ bi, const float* __restrict__ bf_,
                const float* __restrict__ bo, const float* __restrict__ bu,
                bf16_t* __restrict__ H, float* __restrict__ C, int Pa)
{
    __shared__ __align__(16) char smem[52224];
    bf16_t (*XA)[136] = (bf16_t(*)[136])(smem);
    bf16_t (*Hd)[136] = (bf16_t(*)[136])(smem + 8704);
    float  (*SC)[132] = (float(*)[132])(smem);
    bf16_t (*BH)[136] = (bf16_t(*)[136])(smem + 17408);
    bf16_t (*BC)[136] = (bf16_t(*)[136])(smem + 34816);

    const int tid = threadIdx.x;
    const int sA0 = Pa + 32 * blockIdx.x;

    for (int q = 0; q < 2; q++)
        leaf32(x, SW, bi, bo, bu, XA, BH, BC,
               2 * sA0 + 32 * q, 32, 32 * q, tid);

    compute32(x, SW, bi, bf_, bo, bu, XA, SC,
              (const bf16_t(*)[136])BH,
              nullptr, 0, (const bf16_t(*)[136])BC, true,
              sA0, 32,
              nullptr, nullptr, 0,
              H, C, sA0, Hd, false, tid);
}

// ---------------------------------------------------------------------------
// k_pair: block = 32 level-A parents (shifted base Pa + 32t). Generic
// internal pair (B from global bottom h/c). R7 structure, verified.
__global__ __launch_bounds__(256)
void k_pair(const float* __restrict__ x, const bf16_t* __restrict__ SW,
            const float* __restrict__ bi, const float* __restrict__ bf_,
            const float* __restrict__ bo, const float* __restrict__ bu,
            bf16_t* __restrict__ H, float* __restrict__ C,
            int Pa)
{
    __shared__ __align__(16) char smem[60928];
    bf16_t (*XA)[136] = (bf16_t(*)[136])(smem);            //  8704 staging
    bf16_t (*HC)[136] = (bf16_t(*)[136])(smem + 8704);     // 17408 bottom-h staging / Hd
    float  (*SC)[132] = (float(*)[132])(smem);             // 16896 scratch (alias, post-K)
    bf16_t (*BH)[136] = (bf16_t(*)[136])(smem + 26112);    // 17408 mid h
    bf16_t (*BC)[136] = (bf16_t(*)[136])(smem + 43520);    // 17408 mid c (bf16)

    const int tid = threadIdx.x;
    const int t   = blockIdx.x;
    const int sA0 = Pa + 32 * t;
    int Pta = Pa - 32 * t; if (Pta > 32) Pta = 32;

    if (Pta < 32) {
        bf16x8 z = (bf16x8)(bf16_t)0.f;
        for (int i = tid; i < 64 * 17; i += 256) {
            ((bf16x8*)BH)[i] = z;
            ((bf16x8*)BC)[i] = z;
        }
    }

    for (int q = 0; q < 2; q++) {
        int bvalid = 2 * Pa - (64 * t + 32 * q);
        if (bvalid > 32) bvalid = 32;
        if (bvalid <= 0) break;
        {
            int r = tid >> 2, cb = (tid & 3) * 32;
            if (r < 2 * bvalid) {
                const uint4* src = (const uint4*)(H + (size_t)(4 * sA0 + 64 * q + r) * 128 + cb);
                *(uint4*)&HC[r][cb]      = src[0];
                *(uint4*)&HC[r][cb + 8]  = src[1];
                *(uint4*)&HC[r][cb + 16] = src[2];
                *(uint4*)&HC[r][cb + 24] = src[3];
            } else {
                uint4 z = {0u, 0u, 0u, 0u};
                *(uint4*)&HC[r][cb]      = z;
                *(uint4*)&HC[r][cb + 8]  = z;
                *(uint4*)&HC[r][cb + 16] = z;
                *(uint4*)&HC[r][cb + 24] = z;
            }
        }
        compute32(x, SW, bi, bf_, bo, bu, XA, SC,
                  (const bf16_t(*)[136])HC,
                  C, 4 * sA0 + 64 * q, nullptr, false,
                  2 * sA0 + 32 * q, bvalid,
                  BH, BC, 32 * q,
                  nullptr, nullptr, 0, nullptr, true, tid);
    }

    compute32(x, SW, bi, bf_, bo, bu, XA, SC,
              (const bf16_t(*)[136])BH,
              nullptr, 0, (const bf16_t(*)[136])BC, true,
              sA0, Pta,
              nullptr, nullptr, 0,
              H, C, sA0, HC, false, tid);
}

// ---------------------------------------------------------------------------
// k_lvl: ONE level (np = 2^l parents). Task/block = (mt, ct): 32 parents x
// 16 cols. Waves split K (wave = one K=32 slice), partials reduced via LDS,
// wave 0 runs the epilogue and writes h (bf16) / c (f32) straight to global.
// LDS: PR[12][4][64] f32x4 @0 (49152) | XA[32][136] @49152 | CH[64][136]
// @57856 | SC[32][17] f32 aliases PR head. (Unchanged from R11 — verified.)
__global__ __launch_bounds__(256, 2)
void k_lvl(const float* __restrict__ x, const bf16_t* __restrict__ SW,
           const float* __restrict__ bi, const float* __restrict__ bf_,
           const float* __restrict__ bo, const float* __restrict__ bu,
           bf16_t* H, float* C, int np)
{
    __shared__ __align__(16) char smem[75264];
    f32x4  (*PR)[4][64] = (f32x4(*)[4][64])smem;
    bf16_t (*XA)[136]   = (bf16_t(*)[136])(smem + 49152);
    bf16_t (*CH)[136]   = (bf16_t(*)[136])(smem + 57856);
    float  (*SC)[17]    = (float(*)[17])smem;

    const int tid = threadIdx.x;
    const int wave = tid >> 6, lane = tid & 63;
    const int quad = lane >> 4, lc = lane & 15;

    const int task = blockIdx.x;
    const int ct = task & 7, mt = task >> 3;
    int valid = np - 32 * mt; if (valid > 32) valid = 32;
    if (valid <= 0) return;
    const int prow = np + 32 * mt;
    const int crow = 2 * np + 64 * mt;

    {   // stage XA
        int r = tid >> 3, cb = (tid & 7) * 16;
        if (r < valid) cvt16(x + (size_t)(prow - 1 + r) * 128 + cb, &XA[r][cb]);
        else           zero16(&XA[r][cb]);
    }
    {   // stage CH
        int r = tid >> 2, cb = (tid & 3) * 32;
        if (r < 2 * valid) {
            const uint4* src = (const uint4*)(H + (size_t)(crow + r) * 128 + cb);
            *(uint4*)&CH[r][cb]      = src[0];
            *(uint4*)&CH[r][cb + 8]  = src[1];
            *(uint4*)&CH[r][cb + 16] = src[2];
            *(uint4*)&CH[r][cb + 24] = src[3];
        } else {
            uint4 z = {0u, 0u, 0u, 0u};
            *(uint4*)&CH[r][cb]      = z;
            *(uint4*)&CH[r][cb + 8]  = z;
            *(uint4*)&CH[r][cb + 16] = z;
            *(uint4*)&CH[r][cb + 24] = z;
        }
    }
    __syncthreads();

    f32x4 z4 = (f32x4){0.f, 0.f, 0.f, 0.f};
    f32x4 aI0 = z4, aI1 = z4, aXf0 = z4, aXf1 = z4;
    f32x4 aO0 = z4, aO1 = z4, aU0 = z4, aU1 = z4;
    f32x4 aF0 = z4, aF1 = z4, aF2 = z4, aF3 = z4;
    {
        const int k0 = wave * 32 + quad * 8;
        bf16x8 xa0 = *(const bf16x8*)&XA[lc][k0];
        bf16x8 xa1 = *(const bf16x8*)&XA[16 + lc][k0];
        bf16x8 h00 = *(const bf16x8*)&CH[2 * lc][k0];
        bf16x8 h01 = *(const bf16x8*)&CH[2 * lc + 1][k0];
        bf16x8 h10 = *(const bf16x8*)&CH[2 * lc + 32][k0];
        bf16x8 h11 = *(const bf16x8*)&CH[2 * lc + 33][k0];
        bf16x8 at0, at1;
#pragma unroll
        for (int j = 0; j < 8; j++) {
            at0[j] = (bf16_t)((float)h00[j] + (float)h01[j]);
            at1[j] = (bf16_t)((float)h10[j] + (float)h11[j]);
        }
        bf16x8 ac0 = *(const bf16x8*)&CH[lc][k0];
        bf16x8 ac1 = *(const bf16x8*)&CH[16 + lc][k0];
        bf16x8 ac2 = *(const bf16x8*)&CH[32 + lc][k0];
        bf16x8 ac3 = *(const bf16x8*)&CH[48 + lc][k0];

        const size_t boff = ((size_t)(ct * 4 + wave) * 64 + lane) * 8;
        bf16x8 bWi = *(const bf16x8*)(SW + boff);
        bf16x8 bWf = *(const bf16x8*)(SW + 16384 + boff);
        bf16x8 bWo = *(const bf16x8*)(SW + 32768 + boff);
        bf16x8 bWu = *(const bf16x8*)(SW + 49152 + boff);
        const bf16_t* Ub = SW + 65536;
        bf16x8 bIh = *(const bf16x8*)(Ub + boff);
        bf16x8 bIl = *(const bf16x8*)(Ub + 16384 + boff);
        bf16x8 bFh = *(const bf16x8*)(Ub + 32768 + boff);
        bf16x8 bFl = *(const bf16x8*)(Ub + 49152 + boff);
        bf16x8 bOh = *(const bf16x8*)(Ub + 65536 + boff);
        bf16x8 bOl = *(const bf16x8*)(Ub + 81920 + boff);
        bf16x8 bUh = *(const bf16x8*)(Ub + 98304 + boff);
        bf16x8 bUl = *(const bf16x8*)(Ub + 114688 + boff);

        aI0  = MFMA16(xa0, bWi, aI0);  aI1  = MFMA16(xa1, bWi, aI1);
        aXf0 = MFMA16(xa0, bWf, aXf0); aXf1 = MFMA16(xa1, bWf, aXf1);
        aO0  = MFMA16(xa0, bWo, aO0);  aO1  = MFMA16(xa1, bWo, aO1);
        aU0  = MFMA16(xa0, bWu, aU0);  aU1  = MFMA16(xa1, bWu, aU1);
        aI0 = MFMA16(at0, bIh, aI0); aI0 = MFMA16(at0, bIl, aI0);
        aI1 = MFMA16(at1, bIh, aI1); aI1 = MFMA16(at1, bIl, aI1);
        aO0 = MFMA16(at0, bOh, aO0); aO0 = MFMA16(at0, bOl, aO0);
        aO1 = MFMA16(at1, bOh, aO1); aO1 = MFMA16(at1, bOl, aO1);
        aU0 = MFMA16(at0, bUh, aU0); aU0 = MFMA16(at0, bUl, aU0);
        aU1 = MFMA16(at1, bUh, aU1); aU1 = MFMA16(at1, bUl, aU1);
        aF0 = MFMA16(ac0, bFh, aF0); aF0 = MFMA16(ac0, bFl, aF0);
        aF1 = MFMA16(ac1, bFh, aF1); aF1 = MFMA16(ac1, bFl, aF1);
        aF2 = MFMA16(ac2, bFh, aF2); aF2 = MFMA16(ac2, bFl, aF2);
        aF3 = MFMA16(ac3, bFh, aF3); aF3 = MFMA16(ac3, bFl, aF3);
    }
    if (wave != 0) {
        PR[0][wave][lane]  = aI0;  PR[1][wave][lane]  = aI1;
        PR[2][wave][lane]  = aXf0; PR[3][wave][lane]  = aXf1;
        PR[4][wave][lane]  = aO0;  PR[5][wave][lane]  = aO1;
        PR[6][wave][lane]  = aU0;  PR[7][wave][lane]  = aU1;
        PR[8][wave][lane]  = aF0;  PR[9][wave][lane]  = aF1;
        PR[10][wave][lane] = aF2;  PR[11][wave][lane] = aF3;
    }
    __syncthreads();
    if (wave == 0) {
        aI0  += PR[0][1][lane]  + PR[0][2][lane]  + PR[0][3][lane];
        aI1  += PR[1][1][lane]  + PR[1][2][lane]  + PR[1][3][lane];
        aXf0 += PR[2][1][lane]  + PR[2][2][lane]  + PR[2][3][lane];
        aXf1 += PR[3][1][lane]  + PR[3][2][lane]  + PR[3][3][lane];
        aO0  += PR[4][1][lane]  + PR[4][2][lane]  + PR[4][3][lane];
        aO1  += PR[5][1][lane]  + PR[5][2][lane]  + PR[5][3][lane];
        aU0  += PR[6][1][lane]  + PR[6][2][lane]  + PR[6][3][lane];
        aU1  += PR[7][1][lane]  + PR[7][2][lane]  + PR[7][3][lane];
        aF0  += PR[8][1][lane]  + PR[8][2][lane]  + PR[8][3][lane];
        aF1  += PR[9][1][lane]  + PR[9][2][lane]  + PR[9][3][lane];
        aF2  += PR[10][1][lane] + PR[10][2][lane] + PR[10][3][lane];
        aF3  += PR[11][1][lane] + PR[11][2][lane] + PR[11][3][lane];

        const int colg = ct * 16 + lc;
        float c0v[4][2], c1v[4][2];
#pragma unroll
        for (int m2 = 0; m2 < 4; m2++)
#pragma unroll
            for (int pi = 0; pi < 2; pi++) {
                int pl = m2 * 8 + quad * 2 + pi;
                size_t cr = (size_t)(crow + 2 * pl) * 128 + colg;
                c0v[m2][pi] = C[cr];
                c1v[m2][pi] = C[cr + 128];
            }
        float bfv = bf_[colg];
#pragma unroll
        for (int r = 0; r < 4; r++) {
            SC[quad * 4 + r][lc]      = aXf0[r] + bfv;
            SC[16 + quad * 4 + r][lc] = aXf1[r] + bfv;
        }
#define NS_FPATH(M2, AF)                                            \
        _Pragma("unroll")                                           \
        for (int pi = 0; pi < 2; pi++) {                            \
            int pl = M2 * 8 + quad * 2 + pi;                        \
            float xf = SC[pl][lc];                                  \
            float f0 = sigm(xf + AF[2 * pi]);                       \
            float f1 = sigm(xf + AF[2 * pi + 1]);                   \
            SC[pl][lc] = f0 * c0v[M2][pi] + f1 * c1v[M2][pi];       \
        }
        NS_FPATH(0, aF0) NS_FPATH(1, aF1) NS_FPATH(2, aF2) NS_FPATH(3, aF3)
#undef NS_FPATH
        float bii = bi[colg], boi = bo[colg], bui = bu[colg];
#define NS_IOU(MT, AI, AO, AU)                                      \
        _Pragma("unroll")                                           \
        for (int r = 0; r < 4; r++) {                               \
            int pl = MT * 16 + quad * 4 + r;                        \
            float iv = sigm(AI[r] + bii);                           \
            float ov = sigm(AO[r] + boi);                           \
            float uv = tanh_(AU[r] + bui);                          \
            float cv = iv * uv + SC[pl][lc];                        \
            if (pl < valid) {                                       \
                H[(size_t)(prow + pl) * 128 + colg] = (bf16_t)(ov * tanh_(cv)); \
                C[(size_t)(prow + pl) * 128 + colg] = cv;           \
            }                                                       \
        }
        NS_IOU(0, aI0, aO0, aU0)
        NS_IOU(1, aI1, aO1, aU1)
#undef NS_IOU
    }
}

__global__ __launch_bounds__(256)
void k_out(const bf16_t* __restrict__ H, const float* __restrict__ C,
           float* __restrict__ out)
{
    int t = threadIdx.x;
    if (t < 128)      out[t] = (float)H[128 + t];   // shifted row 1 = root
    else if (t < 256) out[t] = C[t];                // C[128 + (t-128)]
}

// ---------------------------------------------------------------------------
extern "C" void kernel_launch(void* const* d_in, const int* in_sizes, int n_in,
                              void* d_out, int out_size, void* d_ws, size_t ws_size,
                              hipStream_t stream)
{
    const float* x   = (const float*)d_in[0];
    const float* Wi  = (const float*)d_in[1];
    const float* bi  = (const float*)d_in[2];
    const float* Ui  = (const float*)d_in[3];
    const float* Wf  = (const float*)d_in[4];
    const float* bf_ = (const float*)d_in[5];
    const float* Uf  = (const float*)d_in[6];
    const float* Wo  = (const float*)d_in[7];
    const float* bo  = (const float*)d_in[8];
    const float* Uo  = (const float*)d_in[9];
    const float* Wu  = (const float*)d_in[10];
    const float* bu  = (const float*)d_in[11];
    const float* Uu  = (const float*)d_in[12];

    int Ntot  = in_sizes[0] / 128;
    int depth = 31 - __builtin_clz((unsigned)(Ntot + 1)) - 1;

    // workspace: SW 384 KB | H bf16 (Ntot+1)*128 | C fp32 (Ntot+1)*128
    char* w = (char*)d_ws;
    bf16_t* SW = (bf16_t*)w;  w += 393216;
    bf16_t* H  = (bf16_t*)w;  w += (size_t)(Ntot + 1) * 128 * sizeof(bf16_t);
    float*  C  = (float*)w;

    k_prep<<<8, 256, 0, stream>>>(Wi, Wf, Wo, Wu, Ui, Uf, Uo, Uu, SW);

    {   // A = depth-1, B = leaves (3 blocks/CU leaf-specialized pair)
        int Pa = 1 << (depth - 1);
        k_pairleaf<<<Pa / 32, 256, 0, stream>>>(x, SW, bi, bf_, bo, bu, H, C, Pa);
    }
    int lowest = depth - 1;
    for (int A = depth - 3; A >= 14; A -= 2) {   // big internal pairs
        int Pa = 1 << A;
        int blocks = (Pa + 31) / 32;
        k_pair<<<blocks, 256, 0, stream>>>(x, SW, bi, bf_, bo, bu, H, C, Pa);
        lowest = A;
    }
    // remaining levels: one latency-optimized launch per level
    for (int l = lowest - 1; l >= 0; l--) {
        int np = 1 << l;
        int nmt = (np + 31) / 32;
        k_lvl<<<nmt * 8, 256, 0, stream>>>(x, SW, bi, bf_, bo, bu, H, C, np);
    }
    k_out<<<1, 256, 0, stream>>>(H, C, (float*)d_out);
}

// Round 9
// 514.823 us; speedup vs baseline: 1.3617x; 1.0251x over previous
//
#include <hip/hip_runtime.h>
#include <hip/hip_bf16.h>

// ChildSumTreeLSTM, fp32 in/out, depth=17, N=2^18-1, D_IN=H=128.
// R7: rcp-based sigm/tanh.
// R11 (511 us): k_pair leaf pair + k_pair A=14 + k_lvl per level 13..0.
// R14 (REVERTED): __launch_bounds__(256,3) forced VGPR 84 -> accumulator
//      spills (+188 MB scratch writes). Never min-waves-force below the
//      accumulator working set (~96 VGPR acc + frags ~ 170).
// R15: leaf64 — merge the two 32-row leaf phases into ONE 64-row phase
//      (4 row-tiles/wave; B-frags shared across row-tiles so loads stay 24
//      while MFMAs/load double). k_pairleaf = 2 serial phases instead of 3.
//      Plain __launch_bounds__(256).
// Weights: W plain bf16, U split-2 hi/lo bf16 (pre-swizzled to B-frag order).
// h global bf16, c global fp32. Shifted rows: row = node+1.

typedef __bf16 bf16_t;
typedef __bf16 bf16x8 __attribute__((ext_vector_type(8)));
typedef float  f32x4  __attribute__((ext_vector_type(4)));

#define MFMA16(a, b, c) __builtin_amdgcn_mfma_f32_16x16x32_bf16((a), (b), (c), 0, 0, 0)

__device__ __forceinline__ float rcp_(float x) { return __builtin_amdgcn_rcpf(x); }
// bf16-rounded outputs: 1-ulp v_rcp_f32 error is invisible.
__device__ __forceinline__ float sigm(float x) { return rcp_(1.0f + __expf(-x)); }
__device__ __forceinline__ float tanh_(float x) {
    float a = fabsf(x);
    float e = __expf(2.0f * a);
    float t = fmaf(-2.0f, rcp_(e + 1.0f), 1.0f);
    return copysignf(t, x);
}

__device__ __forceinline__ void cvt16(const float* __restrict__ src, bf16_t* __restrict__ dst)
{
    float tmp[16];
    *(float4*)&tmp[0]  = ((const float4*)src)[0];
    *(float4*)&tmp[4]  = ((const float4*)src)[1];
    *(float4*)&tmp[8]  = ((const float4*)src)[2];
    *(float4*)&tmp[12] = ((const float4*)src)[3];
    bf16_t b[16];
#pragma unroll
    for (int j = 0; j < 16; j++) b[j] = (bf16_t)tmp[j];
    *(bf16x8*)&dst[0] = *(bf16x8*)&b[0];
    *(bf16x8*)&dst[8] = *(bf16x8*)&b[8];
}

__device__ __forceinline__ void zero16(bf16_t* __restrict__ dst)
{
    bf16x8 z = (bf16x8)(bf16_t)0.f;
    *(bf16x8*)&dst[0] = z;
    *(bf16x8*)&dst[8] = z;
}

// SW layout (bf16 elems): W g (0=Wi 1=Wf 2=Wo 3=Wu) at g*16384, plain.
// U u (0=Ui 1=Uf 2=Uo 3=Uu) at 65536 + u*32768 (hi), +16384 (lo).
// idx = ((nt*4+kb)*64 + lane)*8 + j ; elem = M[kb*32+(lane>>4)*8+j][nt*16+(lane&15)]
__global__ __launch_bounds__(256)
void k_prep(const float* __restrict__ Wi, const float* __restrict__ Wf,
            const float* __restrict__ Wo, const float* __restrict__ Wu,
            const float* __restrict__ Ui, const float* __restrict__ Uf,
            const float* __restrict__ Uo, const float* __restrict__ Uu,
            bf16_t* __restrict__ SW)
{
    int b = blockIdx.x;
    const float* src;
    switch (b) {
        case 0: src = Wi; break; case 1: src = Wf; break;
        case 2: src = Wo; break; case 3: src = Wu; break;
        case 4: src = Ui; break; case 5: src = Uf; break;
        case 6: src = Uo; break; default: src = Uu; break;
    }
    if (b < 4) {
        bf16_t* hi = SW + (size_t)b * 16384;
        for (int idx = threadIdx.x; idx < 16384; idx += 256) {
            int j = idx & 7, ln = (idx >> 3) & 63, kb = (idx >> 9) & 3, nt = idx >> 11;
            int k = kb * 32 + (ln >> 4) * 8 + j;
            int n = nt * 16 + (ln & 15);
            hi[idx] = (bf16_t)src[k * 128 + n];
        }
    } else {
        bf16_t* hi = SW + 65536 + (size_t)(b - 4) * 32768;
        bf16_t* lo = hi + 16384;
        for (int idx = threadIdx.x; idx < 16384; idx += 256) {
            int j = idx & 7, ln = (idx >> 3) & 63, kb = (idx >> 9) & 3, nt = idx >> 11;
            int k = kb * 32 + (ln >> 4) * 8 + j;
            int n = nt * 16 + (ln & 15);
            float w = src[k * 128 + n];
            bf16_t hh = (bf16_t)w;
            hi[idx] = hh;
            lo[idx] = (bf16_t)(w - (float)hh);
        }
    }
}

// ---------------------------------------------------------------------------
// leaf64: 64 leaf rows in ONE phase. 4 row-tiles per wave, 2 col-tiles,
// 3 gates. B-frag loads (24/wave) shared across row-tiles (4 MFMAs/load).
// Acc = 24 f32x4 = 96 VGPR. Writes BH/BC (LDS, bf16) rows 0..63.
__device__ __forceinline__ void leaf64(
    const float* __restrict__ x, const bf16_t* __restrict__ SW,
    const float* __restrict__ bi, const float* __restrict__ bo,
    const float* __restrict__ bu,
    bf16_t (* __restrict__ XA)[136],
    bf16_t (* __restrict__ BH)[136], bf16_t (* __restrict__ BC)[136],
    int xRowBase, int tid)
{
    {
        int r = tid >> 3, cb = (tid & 7) * 16;
        cvt16(x + (size_t)(xRowBase + r - 1) * 128 + cb, &XA[r][cb]);
        cvt16(x + (size_t)(xRowBase + r + 31) * 128 + cb, &XA[r + 32][cb]);
    }
    __syncthreads();
    const int wave = tid >> 6, lane = tid & 63;
    const int quad = lane >> 4, lc = lane & 15;

    f32x4 aI[2][4], aO[2][4], aU[2][4];
#pragma unroll
    for (int nt = 0; nt < 2; nt++)
#pragma unroll
        for (int mt = 0; mt < 4; mt++) {
            aI[nt][mt] = (f32x4){0.f, 0.f, 0.f, 0.f};
            aO[nt][mt] = (f32x4){0.f, 0.f, 0.f, 0.f};
            aU[nt][mt] = (f32x4){0.f, 0.f, 0.f, 0.f};
        }
    for (int kb = 0; kb < 4; kb++) {
        const int k0 = kb * 32 + quad * 8;
        bf16x8 a0 = *(const bf16x8*)&XA[lc][k0];
        bf16x8 a1 = *(const bf16x8*)&XA[16 + lc][k0];
        bf16x8 a2 = *(const bf16x8*)&XA[32 + lc][k0];
        bf16x8 a3 = *(const bf16x8*)&XA[48 + lc][k0];
#pragma unroll
        for (int nt = 0; nt < 2; nt++) {
            const size_t boff = ((size_t)((2 * wave + nt) * 4 + kb) * 64 + lane) * 8;
            bf16x8 bWi = *(const bf16x8*)(SW + boff);
            bf16x8 bWo = *(const bf16x8*)(SW + 32768 + boff);
            bf16x8 bWu = *(const bf16x8*)(SW + 49152 + boff);
            aI[nt][0] = MFMA16(a0, bWi, aI[nt][0]);
            aI[nt][1] = MFMA16(a1, bWi, aI[nt][1]);
            aI[nt][2] = MFMA16(a2, bWi, aI[nt][2]);
            aI[nt][3] = MFMA16(a3, bWi, aI[nt][3]);
            aO[nt][0] = MFMA16(a0, bWo, aO[nt][0]);
            aO[nt][1] = MFMA16(a1, bWo, aO[nt][1]);
            aO[nt][2] = MFMA16(a2, bWo, aO[nt][2]);
            aO[nt][3] = MFMA16(a3, bWo, aO[nt][3]);
            aU[nt][0] = MFMA16(a0, bWu, aU[nt][0]);
            aU[nt][1] = MFMA16(a1, bWu, aU[nt][1]);
            aU[nt][2] = MFMA16(a2, bWu, aU[nt][2]);
            aU[nt][3] = MFMA16(a3, bWu, aU[nt][3]);
        }
    }
#pragma unroll
    for (int nt = 0; nt < 2; nt++) {
        const int col = (2 * wave + nt) * 16 + lc;
        float bii = bi[col], boi = bo[col], bui = bu[col];
#pragma unroll
        for (int mt = 0; mt < 4; mt++)
#pragma unroll
            for (int r = 0; r < 4; r++) {
                float iv = sigm(aI[nt][mt][r] + bii);
                float ov = sigm(aO[nt][mt][r] + boi);
                float uv = tanh_(aU[nt][mt][r] + bui);
                float cv = iv * uv;
                int pl = mt * 16 + quad * 4 + r;
                BH[pl][col] = (bf16_t)(ov * tanh_(cv));
                BC[pl][col] = (bf16_t)cv;
            }
    }
    __syncthreads();
}

// ---------------------------------------------------------------------------
// 32 internal nodes: x@W (4 gates) + ht@[Ui|Uo|Uu] + hc@Uf (split-2) + update.
__device__ __forceinline__ void compute32(
    const float* __restrict__ x, const bf16_t* __restrict__ SW,
    const float* __restrict__ bi, const float* __restrict__ bf_,
    const float* __restrict__ bo, const float* __restrict__ bu,
    bf16_t (* __restrict__ XA)[136], float (* __restrict__ SC)[132],
    const bf16_t (* __restrict__ CH)[136],
    const float* __restrict__ Cglob, int ccBase,
    const bf16_t (* __restrict__ BCc)[136], bool ccLds,
    int xRowBase, int valid,
    bf16_t (* __restrict__ BHo)[136], bf16_t (* __restrict__ BCo)[136], int outRowOff,
    bf16_t* __restrict__ Hg, float* __restrict__ Cg, int outBase,
    bf16_t (* __restrict__ Hd)[136], bool outLds, int tid)
{
    {
        int r = tid >> 3, cb = (tid & 7) * 16;
        if (r < valid) cvt16(x + (size_t)(xRowBase + r - 1) * 128 + cb, &XA[r][cb]);
        else           zero16(&XA[r][cb]);
    }
    __syncthreads();

    const int wave = tid >> 6, lane = tid & 63;
    const int quad = lane >> 4, lc = lane & 15;

    f32x4 aI[2][2], aO[2][2], aU[2][2], aXf[2][2], aF[2][4];
#pragma unroll
    for (int nt = 0; nt < 2; nt++) {
#pragma unroll
        for (int mt = 0; mt < 2; mt++) {
            aI[nt][mt]  = (f32x4){0.f, 0.f, 0.f, 0.f};
            aO[nt][mt]  = (f32x4){0.f, 0.f, 0.f, 0.f};
            aU[nt][mt]  = (f32x4){0.f, 0.f, 0.f, 0.f};
            aXf[nt][mt] = (f32x4){0.f, 0.f, 0.f, 0.f};
        }
#pragma unroll
        for (int mt = 0; mt < 4; mt++) aF[nt][mt] = (f32x4){0.f, 0.f, 0.f, 0.f};
    }

    for (int kb = 0; kb < 4; kb++) {
        const int k0 = kb * 32 + quad * 8;
        bf16x8 xa0 = *(const bf16x8*)&XA[lc][k0];
        bf16x8 xa1 = *(const bf16x8*)&XA[16 + lc][k0];
        bf16x8 h00 = *(const bf16x8*)&CH[2 * lc][k0];
        bf16x8 h01 = *(const bf16x8*)&CH[2 * lc + 1][k0];
        bf16x8 h10 = *(const bf16x8*)&CH[2 * lc + 32][k0];
        bf16x8 h11 = *(const bf16x8*)&CH[2 * lc + 33][k0];
        bf16x8 at0, at1;
#pragma unroll
        for (int j = 0; j < 8; j++) {
            at0[j] = (bf16_t)((float)h00[j] + (float)h01[j]);
            at1[j] = (bf16_t)((float)h10[j] + (float)h11[j]);
        }
        bf16x8 ac0 = *(const bf16x8*)&CH[lc][k0];
        bf16x8 ac1 = *(const bf16x8*)&CH[16 + lc][k0];
        bf16x8 ac2 = *(const bf16x8*)&CH[32 + lc][k0];
        bf16x8 ac3 = *(const bf16x8*)&CH[48 + lc][k0];
#pragma unroll
        for (int nt = 0; nt < 2; nt++) {
            const size_t boff = ((size_t)((2 * wave + nt) * 4 + kb) * 64 + lane) * 8;
            bf16x8 bWi = *(const bf16x8*)(SW + boff);
            bf16x8 bWf = *(const bf16x8*)(SW + 16384 + boff);
            bf16x8 bWo = *(const bf16x8*)(SW + 32768 + boff);
            bf16x8 bWu = *(const bf16x8*)(SW + 49152 + boff);
            aI[nt][0]  = MFMA16(xa0, bWi, aI[nt][0]);
            aI[nt][1]  = MFMA16(xa1, bWi, aI[nt][1]);
            aXf[nt][0] = MFMA16(xa0, bWf, aXf[nt][0]);
            aXf[nt][1] = MFMA16(xa1, bWf, aXf[nt][1]);
            aO[nt][0]  = MFMA16(xa0, bWo, aO[nt][0]);
            aO[nt][1]  = MFMA16(xa1, bWo, aO[nt][1]);
            aU[nt][0]  = MFMA16(xa0, bWu, aU[nt][0]);
            aU[nt][1]  = MFMA16(xa1, bWu, aU[nt][1]);
            const bf16_t* Ub = SW + 65536;
            bf16x8 bIh = *(const bf16x8*)(Ub + boff);
            bf16x8 bIl = *(const bf16x8*)(Ub + 16384 + boff);
            aI[nt][0] = MFMA16(at0, bIh, aI[nt][0]);
            aI[nt][0] = MFMA16(at0, bIl, aI[nt][0]);
            aI[nt][1] = MFMA16(at1, bIh, aI[nt][1]);
            aI[nt][1] = MFMA16(at1, bIl, aI[nt][1]);
            bf16x8 bOh = *(const bf16x8*)(Ub + 65536 + boff);
            bf16x8 bOl = *(const bf16x8*)(Ub + 81920 + boff);
            aO[nt][0] = MFMA16(at0, bOh, aO[nt][0]);
            aO[nt][0] = MFMA16(at0, bOl, aO[nt][0]);
            aO[nt][1] = MFMA16(at1, bOh, aO[nt][1]);
            aO[nt][1] = MFMA16(at1, bOl, aO[nt][1]);
            bf16x8 bUh = *(const bf16x8*)(Ub + 98304 + boff);
            bf16x8 bUl = *(const bf16x8*)(Ub + 114688 + boff);
            aU[nt][0] = MFMA16(at0, bUh, aU[nt][0]);
            aU[nt][0] = MFMA16(at0, bUl, aU[nt][0]);
            aU[nt][1] = MFMA16(at1, bUh, aU[nt][1]);
            aU[nt][1] = MFMA16(at1, bUl, aU[nt][1]);
            bf16x8 bFh = *(const bf16x8*)(Ub + 32768 + boff);
            bf16x8 bFl = *(const bf16x8*)(Ub + 49152 + boff);
            aF[nt][0] = MFMA16(ac0, bFh, aF[nt][0]);
            aF[nt][0] = MFMA16(ac0, bFl, aF[nt][0]);
            aF[nt][1] = MFMA16(ac1, bFh, aF[nt][1]);
            aF[nt][1] = MFMA16(ac1, bFl, aF[nt][1]);
            aF[nt][2] = MFMA16(ac2, bFh, aF[nt][2]);
            aF[nt][2] = MFMA16(ac2, bFl, aF[nt][2]);
            aF[nt][3] = MFMA16(ac3, bFh, aF[nt][3]);
            aF[nt][3] = MFMA16(ac3, bFl, aF[nt][3]);
        }
    }
    __syncthreads();   // XA/CH-staging reads done; SC (alias) becomes writable

    // dump xf (+bias) for the f-path row exchange
#pragma unroll
    for (int nt = 0; nt < 2; nt++) {
        const int col = (2 * wave + nt) * 16 + lc;
        float bfv = bf_[col];
#pragma unroll
        for (int mt = 0; mt < 2; mt++)
#pragma unroll
            for (int r = 0; r < 4; r++)
                SC[mt * 16 + quad * 4 + r][col] = aXf[nt][mt][r] + bfv;
    }
    __syncthreads();

    // f-path: S[pl][col] = f0*c0 + f1*c1, children are in-lane reg pairs
    float Sv[2][4][2];
#pragma unroll
    for (int nt = 0; nt < 2; nt++) {
        const int col = (2 * wave + nt) * 16 + lc;
#pragma unroll
        for (int mt = 0; mt < 4; mt++)
#pragma unroll
            for (int pi = 0; pi < 2; pi++) {
                int pl = mt * 8 + quad * 2 + pi;
                float xf = SC[pl][col];
                float f0 = sigm(xf + aF[nt][mt][2 * pi]);
                float f1 = sigm(xf + aF[nt][mt][2 * pi + 1]);
                float c0, c1;
                if (ccLds) {
                    c0 = (float)BCc[2 * pl][col];
                    c1 = (float)BCc[2 * pl + 1][col];
                } else {
                    size_t cr = (size_t)(ccBase + 2 * pl) * 128 + col;
                    c0 = Cglob[cr];
                    c1 = Cglob[cr + 128];
                }
                Sv[nt][mt][pi] = f0 * c0 + f1 * c1;
            }
    }
    __syncthreads();   // all xf reads done -> SC overwritable in place
#pragma unroll
    for (int nt = 0; nt < 2; nt++) {
        const int col = (2 * wave + nt) * 16 + lc;
#pragma unroll
        for (int mt = 0; mt < 4; mt++)
#pragma unroll
            for (int pi = 0; pi < 2; pi++)
                SC[mt * 8 + quad * 2 + pi][col] = Sv[nt][mt][pi];
    }
    __syncthreads();

    // i/o/u + cell update
    float hr[2][2][4];
#pragma unroll
    for (int nt = 0; nt < 2; nt++) {
        const int col = (2 * wave + nt) * 16 + lc;
        float bii = bi[col], boi = bo[col], bui = bu[col];
#pragma unroll
        for (int mt = 0; mt < 2; mt++)
#pragma unroll
            for (int r = 0; r < 4; r++) {
                int pl = mt * 16 + quad * 4 + r;
                float iv = sigm(aI[nt][mt][r] + bii);
                float ov = sigm(aO[nt][mt][r] + boi);
                float uv = tanh_(aU[nt][mt][r] + bui);
                float cv = iv * uv + SC[pl][col];
                float hv = ov * tanh_(cv);
                hr[nt][mt][r] = hv;
                if (outLds) {
                    BHo[outRowOff + pl][col] = (bf16_t)hv;
                    BCo[outRowOff + pl][col] = (bf16_t)cv;
                } else if (pl < valid) {
                    Cg[(size_t)(outBase + pl) * 128 + col] = cv;
                }
            }
    }
    if (outLds) {
        __syncthreads();
    } else {
        __syncthreads();   // SC reads done -> Hd (overlapping region) writable
#pragma unroll
        for (int nt = 0; nt < 2; nt++) {
            const int col = (2 * wave + nt) * 16 + lc;
#pragma unroll
            for (int mt = 0; mt < 2; mt++)
#pragma unroll
                for (int r = 0; r < 4; r++)
                    Hd[mt * 16 + quad * 4 + r][col] = (bf16_t)hr[nt][mt][r];
        }
        __syncthreads();
        int r = tid >> 3, cb = (tid & 7) * 16;
        if (r < valid) {
            uint4* dst = (uint4*)(Hg + (size_t)(outBase + r) * 128 + cb);
            dst[0] = *(uint4*)&Hd[r][cb];
            dst[1] = *(uint4*)&Hd[r][cb + 8];
        }
        __syncthreads();
    }
}

// ---------------------------------------------------------------------------
// k_pairleaf: block = 32 level-A parents, B = leaves. Two phases:
// leaf64 (all 64 leaf children in one GEMM) + compute32 (level A).
// LDS: XA[64][136] @0 (17408) | SC[32][132] f32 @0 alias (post-K) |
//      Hd[32][136] @8704 alias (post-SC-read) | BH[64][136] @17408 |
//      BC[64][136] @34816. Total 52224.
__global__ __launch_bounds__(256)
void k_pairleaf(const float* __restrict__ x, const bf16_t* __restrict__ SW,
                const float* __restrict__ bi, const float* __restrict__ bf_,
                const float* __restrict__ bo, const float* __restrict__ bu,
                bf16_t* __restrict__ H, float* __restrict__ C, int Pa)
{
    __shared__ __align__(16) char smem[52224];
    bf16_t (*XA)[136] = (bf16_t(*)[136])(smem);
    float  (*SC)[132] = (float(*)[132])(smem);
    bf16_t (*Hd)[136] = (bf16_t(*)[136])(smem + 8704);
    bf16_t (*BH)[136] = (bf16_t(*)[136])(smem + 17408);
    bf16_t (*BC)[136] = (bf16_t(*)[136])(smem + 34816);

    const int tid = threadIdx.x;
    const int sA0 = Pa + 32 * blockIdx.x;

    leaf64(x, SW, bi, bo, bu, XA, BH, BC, 2 * sA0, tid);

    compute32(x, SW, bi, bf_, bo, bu, XA, SC,
              (const bf16_t(*)[136])BH,
              nullptr, 0, (const bf16_t(*)[136])BC, true,
              sA0, 32,
              nullptr, nullptr, 0,
              H, C, sA0, Hd, false, tid);
}

// ---------------------------------------------------------------------------
// k_pair: block = 32 level-A parents (shifted base Pa + 32t). Generic
// internal pair (B from global bottom h/c). R7 structure, verified.
__global__ __launch_bounds__(256)
void k_pair(const float* __restrict__ x, const bf16_t* __restrict__ SW,
            const float* __restrict__ bi, const float* __restrict__ bf_,
            const float* __restrict__ bo, const float* __restrict__ bu,
            bf16_t* __restrict__ H, float* __restrict__ C,
            int Pa)
{
    __shared__ __align__(16) char smem[60928];
    bf16_t (*XA)[136] = (bf16_t(*)[136])(smem);            //  8704 staging
    bf16_t (*HC)[136] = (bf16_t(*)[136])(smem + 8704);     // 17408 bottom-h staging / Hd
    float  (*SC)[132] = (float(*)[132])(smem);             // 16896 scratch (alias, post-K)
    bf16_t (*BH)[136] = (bf16_t(*)[136])(smem + 26112);    // 17408 mid h
    bf16_t (*BC)[136] = (bf16_t(*)[136])(smem + 43520);    // 17408 mid c (bf16)

    const int tid = threadIdx.x;
    const int t   = blockIdx.x;
    const int sA0 = Pa + 32 * t;
    int Pta = Pa - 32 * t; if (Pta > 32) Pta = 32;

    if (Pta < 32) {
        bf16x8 z = (bf16x8)(bf16_t)0.f;
        for (int i = tid; i < 64 * 17; i += 256) {
            ((bf16x8*)BH)[i] = z;
            ((bf16x8*)BC)[i] = z;
        }
    }

    for (int q = 0; q < 2; q++) {
        int bvalid = 2 * Pa - (64 * t + 32 * q);
        if (bvalid > 32) bvalid = 32;
        if (bvalid <= 0) break;
        {
            int r = tid >> 2, cb = (tid & 3) * 32;
            if (r < 2 * bvalid) {
                const uint4* src = (const uint4*)(H + (size_t)(4 * sA0 + 64 * q + r) * 128 + cb);
                *(uint4*)&HC[r][cb]      = src[0];
                *(uint4*)&HC[r][cb + 8]  = src[1];
                *(uint4*)&HC[r][cb + 16] = src[2];
                *(uint4*)&HC[r][cb + 24] = src[3];
            } else {
                uint4 z = {0u, 0u, 0u, 0u};
                *(uint4*)&HC[r][cb]      = z;
                *(uint4*)&HC[r][cb + 8]  = z;
                *(uint4*)&HC[r][cb + 16] = z;
                *(uint4*)&HC[r][cb + 24] = z;
            }
        }
        compute32(x, SW, bi, bf_, bo, bu, XA, SC,
                  (const bf16_t(*)[136])HC,
                  C, 4 * sA0 + 64 * q, nullptr, false,
                  2 * sA0 + 32 * q, bvalid,
                  BH, BC, 32 * q,
                  nullptr, nullptr, 0, nullptr, true, tid);
    }

    compute32(x, SW, bi, bf_, bo, bu, XA, SC,
              (const bf16_t(*)[136])BH,
              nullptr, 0, (const bf16_t(*)[136])BC, true,
              sA0, Pta,
              nullptr, nullptr, 0,
              H, C, sA0, HC, false, tid);
}

// ---------------------------------------------------------------------------
// k_lvl: ONE level (np = 2^l parents). Task/block = (mt, ct): 32 parents x
// 16 cols. Waves split K (wave = one K=32 slice), partials reduced via LDS,
// wave 0 runs the epilogue and writes h (bf16) / c (f32) straight to global.
// LDS: PR[12][4][64] f32x4 @0 (49152) | XA[32][136] @49152 | CH[64][136]
// @57856 | SC[32][17] f32 aliases PR head. (Unchanged from R11 — verified.)
__global__ __launch_bounds__(256, 2)
void k_lvl(const float* __restrict__ x, const bf16_t* __restrict__ SW,
           const float* __restrict__ bi, const float* __restrict__ bf_,
           const float* __restrict__ bo, const float* __restrict__ bu,
           bf16_t* H, float* C, int np)
{
    __shared__ __align__(16) char smem[75264];
    f32x4  (*PR)[4][64] = (f32x4(*)[4][64])smem;
    bf16_t (*XA)[136]   = (bf16_t(*)[136])(smem + 49152);
    bf16_t (*CH)[136]   = (bf16_t(*)[136])(smem + 57856);
    float  (*SC)[17]    = (float(*)[17])smem;

    const int tid = threadIdx.x;
    const int wave = tid >> 6, lane = tid & 63;
    const int quad = lane >> 4, lc = lane & 15;

    const int task = blockIdx.x;
    const int ct = task & 7, mt = task >> 3;
    int valid = np - 32 * mt; if (valid > 32) valid = 32;
    if (valid <= 0) return;
    const int prow = np + 32 * mt;
    const int crow = 2 * np + 64 * mt;

    {   // stage XA
        int r = tid >> 3, cb = (tid & 7) * 16;
        if (r < valid) cvt16(x + (size_t)(prow - 1 + r) * 128 + cb, &XA[r][cb]);
        else           zero16(&XA[r][cb]);
    }
    {   // stage CH
        int r = tid >> 2, cb = (tid & 3) * 32;
        if (r < 2 * valid) {
            const uint4* src = (const uint4*)(H + (size_t)(crow + r) * 128 + cb);
            *(uint4*)&CH[r][cb]      = src[0];
            *(uint4*)&CH[r][cb + 8]  = src[1];
            *(uint4*)&CH[r][cb + 16] = src[2];
            *(uint4*)&CH[r][cb + 24] = src[3];
        } else {
            uint4 z = {0u, 0u, 0u, 0u};
            *(uint4*)&CH[r][cb]      = z;
            *(uint4*)&CH[r][cb + 8]  = z;
            *(uint4*)&CH[r][cb + 16] = z;
            *(uint4*)&CH[r][cb + 24] = z;
        }
    }
    __syncthreads();

    f32x4 z4 = (f32x4){0.f, 0.f, 0.f, 0.f};
    f32x4 aI0 = z4, aI1 = z4, aXf0 = z4, aXf1 = z4;
    f32x4 aO0 = z4, aO1 = z4, aU0 = z4, aU1 = z4;
    f32x4 aF0 = z4, aF1 = z4, aF2 = z4, aF3 = z4;
    {
        const int k0 = wave * 32 + quad * 8;
        bf16x8 xa0 = *(const bf16x8*)&XA[lc][k0];
        bf16x8 xa1 = *(const bf16x8*)&XA[16 + lc][k0];
        bf16x8 h00 = *(const bf16x8*)&CH[2 * lc][k0];
        bf16x8 h01 = *(const bf16x8*)&CH[2 * lc + 1][k0];
        bf16x8 h10 = *(const bf16x8*)&CH[2 * lc + 32][k0];
        bf16x8 h11 = *(const bf16x8*)&CH[2 * lc + 33][k0];
        bf16x8 at0, at1;
#pragma unroll
        for (int j = 0; j < 8; j++) {
            at0[j] = (bf16_t)((float)h00[j] + (float)h01[j]);
            at1[j] = (bf16_t)((float)h10[j] + (float)h11[j]);
        }
        bf16x8 ac0 = *(const bf16x8*)&CH[lc][k0];
        bf16x8 ac1 = *(const bf16x8*)&CH[16 + lc][k0];
        bf16x8 ac2 = *(const bf16x8*)&CH[32 + lc][k0];
        bf16x8 ac3 = *(const bf16x8*)&CH[48 + lc][k0];

        const size_t boff = ((size_t)(ct * 4 + wave) * 64 + lane) * 8;
        bf16x8 bWi = *(const bf16x8*)(SW + boff);
        bf16x8 bWf = *(const bf16x8*)(SW + 16384 + boff);
        bf16x8 bWo = *(const bf16x8*)(SW + 32768 + boff);
        bf16x8 bWu = *(const bf16x8*)(SW + 49152 + boff);
        const bf16_t* Ub = SW + 65536;
        bf16x8 bIh = *(const bf16x8*)(Ub + boff);
        bf16x8 bIl = *(const bf16x8*)(Ub + 16384 + boff);
        bf16x8 bFh = *(const bf16x8*)(Ub + 32768 + boff);
        bf16x8 bFl = *(const bf16x8*)(Ub + 49152 + boff);
        bf16x8 bOh = *(const bf16x8*)(Ub + 65536 + boff);
        bf16x8 bOl = *(const bf16x8*)(Ub + 81920 + boff);
        bf16x8 bUh = *(const bf16x8*)(Ub + 98304 + boff);
        bf16x8 bUl = *(const bf16x8*)(Ub + 114688 + boff);

        aI0  = MFMA16(xa0, bWi, aI0);  aI1  = MFMA16(xa1, bWi, aI1);
        aXf0 = MFMA16(xa0, bWf, aXf0); aXf1 = MFMA16(xa1, bWf, aXf1);
        aO0  = MFMA16(xa0, bWo, aO0);  aO1  = MFMA16(xa1, bWo, aO1);
        aU0  = MFMA16(xa0, bWu, aU0);  aU1  = MFMA16(xa1, bWu, aU1);
        aI0 = MFMA16(at0, bIh, aI0); aI0 = MFMA16(at0, bIl, aI0);
        aI1 = MFMA16(at1, bIh, aI1); aI1 = MFMA16(at1, bIl, aI1);
        aO0 = MFMA16(at0, bOh, aO0); aO0 = MFMA16(at0, bOl, aO0);
        aO1 = MFMA16(at1, bOh, aO1); aO1 = MFMA16(at1, bOl, aO1);
        aU0 = MFMA16(at0, bUh, aU0); aU0 = MFMA16(at0, bUl, aU0);
        aU1 = MFMA16(at1, bUh, aU1); aU1 = MFMA16(at1, bUl, aU1);
        aF0 = MFMA16(ac0, bFh, aF0); aF0 = MFMA16(ac0, bFl, aF0);
        aF1 = MFMA16(ac1, bFh, aF1); aF1 = MFMA16(ac1, bFl, aF1);
        aF2 = MFMA16(ac2, bFh, aF2); aF2 = MFMA16(ac2, bFl, aF2);
        aF3 = MFMA16(ac3, bFh, aF3); aF3 = MFMA16(ac3, bFl, aF3);
    }
    if (wave != 0) {
        PR[0][wave][lane]  = aI0;  PR[1][wave][lane]  = aI1;
        PR[2][wave][lane]  = aXf0; PR[3][wave][lane]  = aXf1;
        PR[4][wave][lane]  = aO0;  PR[5][wave][lane]  = aO1;
        PR[6][wave][lane]  = aU0;  PR[7][wave][lane]  = aU1;
        PR[8][wave][lane]  = aF0;  PR[9][wave][lane]  = aF1;
        PR[10][wave][lane] = aF2;  PR[11][wave][lane] = aF3;
    }
    __syncthreads();
    if (wave == 0) {
        aI0  += PR[0][1][lane]  + PR[0][2][lane]  + PR[0][3][lane];
        aI1  += PR[1][1][lane]  + PR[1][2][lane]  + PR[1][3][lane];
        aXf0 += PR[2][1][lane]  + PR[2][2][lane]  + PR[2][3][lane];
        aXf1 += PR[3][1][lane]  + PR[3][2][lane]  + PR[3][3][lane];
        aO0  += PR[4][1][lane]  + PR[4][2][lane]  + PR[4][3][lane];
        aO1  += PR[5][1][lane]  + PR[5][2][lane]  + PR[5][3][lane];
        aU0  += PR[6][1][lane]  + PR[6][2][lane]  + PR[6][3][lane];
        aU1  += PR[7][1][lane]  + PR[7][2][lane]  + PR[7][3][lane];
        aF0  += PR[8][1][lane]  + PR[8][2][lane]  + PR[8][3][lane];
        aF1  += PR[9][1][lane]  + PR[9][2][lane]  + PR[9][3][lane];
        aF2  += PR[10][1][lane] + PR[10][2][lane] + PR[10][3][lane];
        aF3  += PR[11][1][lane] + PR[11][2][lane] + PR[11][3][lane];

        const int colg = ct * 16 + lc;
        float c0v[4][2], c1v[4][2];
#pragma unroll
        for (int m2 = 0; m2 < 4; m2++)
#pragma unroll
            for (int pi = 0; pi < 2; pi++) {
                int pl = m2 * 8 + quad * 2 + pi;
                size_t cr = (size_t)(crow + 2 * pl) * 128 + colg;
                c0v[m2][pi] = C[cr];
                c1v[m2][pi] = C[cr + 128];
            }
        float bfv = bf_[colg];
#pragma unroll
        for (int r = 0; r < 4; r++) {
            SC[quad * 4 + r][lc]      = aXf0[r] + bfv;
            SC[16 + quad * 4 + r][lc] = aXf1[r] + bfv;
        }
#define NS_FPATH(M2, AF)                                            \
        _Pragma("unroll")                                           \
        for (int pi = 0; pi < 2; pi++) {                            \
            int pl = M2 * 8 + quad * 2 + pi;                        \
            float xf = SC[pl][lc];                                  \
            float f0 = sigm(xf + AF[2 * pi]);                       \
            float f1 = sigm(xf + AF[2 * pi + 1]);                   \
            SC[pl][lc] = f0 * c0v[M2][pi] + f1 * c1v[M2][pi];       \
        }
        NS_FPATH(0, aF0) NS_FPATH(1, aF1) NS_FPATH(2, aF2) NS_FPATH(3, aF3)
#undef NS_FPATH
        float bii = bi[colg], boi = bo[colg], bui = bu[colg];
#define NS_IOU(MT, AI, AO, AU)                                      \
        _Pragma("unroll")                                           \
        for (int r = 0; r < 4; r++) {                               \
            int pl = MT * 16 + quad * 4 + r;                        \
            float iv = sigm(AI[r] + bii);                           \
            float ov = sigm(AO[r] + boi);                           \
            float uv = tanh_(AU[r] + bui);                          \
            float cv = iv * uv + SC[pl][lc];                        \
            if (pl < valid) {                                       \
                H[(size_t)(prow + pl) * 128 + colg] = (bf16_t)(ov * tanh_(cv)); \
                C[(size_t)(prow + pl) * 128 + colg] = cv;           \
            }                                                       \
        }
        NS_IOU(0, aI0, aO0, aU0)
        NS_IOU(1, aI1, aO1, aU1)
#undef NS_IOU
    }
}

__global__ __launch_bounds__(256)
void k_out(const bf16_t* __restrict__ H, const float* __restrict__ C,
           float* __restrict__ out)
{
    int t = threadIdx.x;
    if (t < 128)      out[t] = (float)H[128 + t];   // shifted row 1 = root
    else if (t < 256) out[t] = C[t];                // C[128 + (t-128)]
}

// ---------------------------------------------------------------------------
extern "C" void kernel_launch(void* const* d_in, const int* in_sizes, int n_in,
                              void* d_out, int out_size, void* d_ws, size_t ws_size,
                              hipStream_t stream)
{
    const float* x   = (const float*)d_in[0];
    const float* Wi  = (const float*)d_in[1];
    const float* bi  = (const float*)d_in[2];
    const float* Ui  = (const float*)d_in[3];
    const float* Wf  = (const float*)d_in[4];
    const float* bf_ = (const float*)d_in[5];
    const float* Uf  = (const float*)d_in[6];
    const float* Wo  = (const float*)d_in[7];
    const float* bo  = (const float*)d_in[8];
    const float* Uo  = (const float*)d_in[9];
    const float* Wu  = (const float*)d_in[10];
    const float* bu  = (const float*)d_in[11];
    const float* Uu  = (const float*)d_in[12];

    int Ntot  = in_sizes[0] / 128;
    int depth = 31 - __builtin_clz((unsigned)(Ntot + 1)) - 1;

    // workspace: SW 384 KB | H bf16 (Ntot+1)*128 | C fp32 (Ntot+1)*128
    char* w = (char*)d_ws;
    bf16_t* SW = (bf16_t*)w;  w += 393216;
    bf16_t* H  = (bf16_t*)w;  w += (size_t)(Ntot + 1) * 128 * sizeof(bf16_t);
    float*  C  = (float*)w;

    k_prep<<<8, 256, 0, stream>>>(Wi, Wf, Wo, Wu, Ui, Uf, Uo, Uu, SW);

    {   // A = depth-1, B = leaves (2-phase: leaf64 + compute32)
        int Pa = 1 << (depth - 1);
        k_pairleaf<<<Pa / 32, 256, 0, stream>>>(x, SW, bi, bf_, bo, bu, H, C, Pa);
    }
    int lowest = depth - 1;
    for (int A = depth - 3; A >= 14; A -= 2) {   // big internal pairs
        int Pa = 1 << A;
        int blocks = (Pa + 31) / 32;
        k_pair<<<blocks, 256, 0, stream>>>(x, SW, bi, bf_, bo, bu, H, C, Pa);
        lowest = A;
    }
    // remaining levels: one latency-optimized launch per level
    for (int l = lowest - 1; l >= 0; l--) {
        int np = 1 << l;
        int nmt = (np + 31) / 32;
        k_lvl<<<nmt * 8, 256, 0, stream>>>(x, SW, bi, bf_, bo, bu, H, C, np);
    }
    k_out<<<1, 256, 0, stream>>>(H, C, (float*)d_out);
}

// Round 11
// 470.796 us; speedup vs baseline: 1.4890x; 1.0935x over previous
//
#include <hip/hip_runtime.h>
#include <hip/hip_bf16.h>

// ChildSumTreeLSTM, fp32 in/out, depth=17, N=2^18-1, D_IN=H=128.
// R7: rcp-based sigm/tanh.
// R11/R5 (511 us, verified): k_pair leaf + k_pair A=14 + k_lvl 13..0.
// R16 (FAILED 3.9 absmax): simultaneous k_pairleaf2 + k_pair2 rewrite.
// R17 (bisect): verified base (internal k_pair for A=14 + k_lvl 13..0) with
//      ONLY the leaf kernel replaced by k_pairleaf2: 512 thr, 8 waves, wave =
//      one 16-col tile for both the 64-leaf GEMM (leaf64_wave) and the
//      level-16 parents (node32_wave, k_lvl's verified single-wave epilogue).
//      Halves the per-wave weight-load chain (96 -> 48) and accumulator
//      pressure (24 -> 12 f32x4) on the top dispatch. Full-validity only —
//      none of R16's partial-row logic.
// Weights: W plain bf16, U split-2 hi/lo bf16 (pre-swizzled to B-frag order).
// h global bf16, c global fp32. Shifted rows: row = node+1.

typedef __bf16 bf16_t;
typedef __bf16 bf16x8 __attribute__((ext_vector_type(8)));
typedef float  f32x4  __attribute__((ext_vector_type(4)));

#define MFMA16(a, b, c) __builtin_amdgcn_mfma_f32_16x16x32_bf16((a), (b), (c), 0, 0, 0)

__device__ __forceinline__ float rcp_(float x) { return __builtin_amdgcn_rcpf(x); }
// bf16-rounded outputs: 1-ulp v_rcp_f32 error is invisible.
__device__ __forceinline__ float sigm(float x) { return rcp_(1.0f + __expf(-x)); }
__device__ __forceinline__ float tanh_(float x) {
    float a = fabsf(x);
    float e = __expf(2.0f * a);
    float t = fmaf(-2.0f, rcp_(e + 1.0f), 1.0f);
    return copysignf(t, x);
}

__device__ __forceinline__ void cvt16(const float* __restrict__ src, bf16_t* __restrict__ dst)
{
    float tmp[16];
    *(float4*)&tmp[0]  = ((const float4*)src)[0];
    *(float4*)&tmp[4]  = ((const float4*)src)[1];
    *(float4*)&tmp[8]  = ((const float4*)src)[2];
    *(float4*)&tmp[12] = ((const float4*)src)[3];
    bf16_t b[16];
#pragma unroll
    for (int j = 0; j < 16; j++) b[j] = (bf16_t)tmp[j];
    *(bf16x8*)&dst[0] = *(bf16x8*)&b[0];
    *(bf16x8*)&dst[8] = *(bf16x8*)&b[8];
}

__device__ __forceinline__ void zero16(bf16_t* __restrict__ dst)
{
    bf16x8 z = (bf16x8)(bf16_t)0.f;
    *(bf16x8*)&dst[0] = z;
    *(bf16x8*)&dst[8] = z;
}

// SW layout (bf16 elems): W g (0=Wi 1=Wf 2=Wo 3=Wu) at g*16384, plain.
// U u (0=Ui 1=Uf 2=Uo 3=Uu) at 65536 + u*32768 (hi), +16384 (lo).
// idx = ((nt*4+kb)*64 + lane)*8 + j ; elem = M[kb*32+(lane>>4)*8+j][nt*16+(lane&15)]
__global__ __launch_bounds__(256)
void k_prep(const float* __restrict__ Wi, const float* __restrict__ Wf,
            const float* __restrict__ Wo, const float* __restrict__ Wu,
            const float* __restrict__ Ui, const float* __restrict__ Uf,
            const float* __restrict__ Uo, const float* __restrict__ Uu,
            bf16_t* __restrict__ SW)
{
    int b = blockIdx.x;
    const float* src;
    switch (b) {
        case 0: src = Wi; break; case 1: src = Wf; break;
        case 2: src = Wo; break; case 3: src = Wu; break;
        case 4: src = Ui; break; case 5: src = Uf; break;
        case 6: src = Uo; break; default: src = Uu; break;
    }
    if (b < 4) {
        bf16_t* hi = SW + (size_t)b * 16384;
        for (int idx = threadIdx.x; idx < 16384; idx += 256) {
            int j = idx & 7, ln = (idx >> 3) & 63, kb = (idx >> 9) & 3, nt = idx >> 11;
            int k = kb * 32 + (ln >> 4) * 8 + j;
            int n = nt * 16 + (ln & 15);
            hi[idx] = (bf16_t)src[k * 128 + n];
        }
    } else {
        bf16_t* hi = SW + 65536 + (size_t)(b - 4) * 32768;
        bf16_t* lo = hi + 16384;
        for (int idx = threadIdx.x; idx < 16384; idx += 256) {
            int j = idx & 7, ln = (idx >> 3) & 63, kb = (idx >> 9) & 3, nt = idx >> 11;
            int k = kb * 32 + (ln >> 4) * 8 + j;
            int n = nt * 16 + (ln & 15);
            float w = src[k * 128 + n];
            bf16_t hh = (bf16_t)w;
            hi[idx] = hh;
            lo[idx] = (bf16_t)(w - (float)hh);
        }
    }
}

// ---------------------------------------------------------------------------
// node32_wave: ONE wave computes 32 internal nodes x 16 cols (col-tile ct),
// full K=128. Children h from CH (LDS, 64 rows), children c from BCc (LDS
// bf16). Output: global H (bf16) / C (fp32). Epilogue = k_lvl's verified
// single-wave path (SCw = wave-private LDS [32][17] f32).
__device__ __forceinline__ void node32_wave(
    const bf16_t* __restrict__ SW,
    const float* __restrict__ bi, const float* __restrict__ bf_,
    const float* __restrict__ bo, const float* __restrict__ bu,
    const bf16_t (* __restrict__ XA)[136],
    const bf16_t (* __restrict__ CH)[136],
    const bf16_t (* __restrict__ BCc)[136],
    float (* __restrict__ SCw)[17],
    int ct,
    bf16_t* __restrict__ Hg, float* __restrict__ Cg, int outBase,
    int lane)
{
    const int quad = lane >> 4, lc = lane & 15;
    f32x4 z4 = (f32x4){0.f, 0.f, 0.f, 0.f};
    f32x4 aI0 = z4, aI1 = z4, aXf0 = z4, aXf1 = z4;
    f32x4 aO0 = z4, aO1 = z4, aU0 = z4, aU1 = z4;
    f32x4 aF0 = z4, aF1 = z4, aF2 = z4, aF3 = z4;

#pragma unroll
    for (int kb = 0; kb < 4; kb++) {
        const int k0 = kb * 32 + quad * 8;
        bf16x8 xa0 = *(const bf16x8*)&XA[lc][k0];
        bf16x8 xa1 = *(const bf16x8*)&XA[16 + lc][k0];
        bf16x8 h00 = *(const bf16x8*)&CH[2 * lc][k0];
        bf16x8 h01 = *(const bf16x8*)&CH[2 * lc + 1][k0];
        bf16x8 h10 = *(const bf16x8*)&CH[2 * lc + 32][k0];
        bf16x8 h11 = *(const bf16x8*)&CH[2 * lc + 33][k0];
        bf16x8 at0, at1;
#pragma unroll
        for (int j = 0; j < 8; j++) {
            at0[j] = (bf16_t)((float)h00[j] + (float)h01[j]);
            at1[j] = (bf16_t)((float)h10[j] + (float)h11[j]);
        }
        bf16x8 ac0 = *(const bf16x8*)&CH[lc][k0];
        bf16x8 ac1 = *(const bf16x8*)&CH[16 + lc][k0];
        bf16x8 ac2 = *(const bf16x8*)&CH[32 + lc][k0];
        bf16x8 ac3 = *(const bf16x8*)&CH[48 + lc][k0];

        const size_t boff = ((size_t)(ct * 4 + kb) * 64 + lane) * 8;
        bf16x8 bWi = *(const bf16x8*)(SW + boff);
        bf16x8 bWf = *(const bf16x8*)(SW + 16384 + boff);
        bf16x8 bWo = *(const bf16x8*)(SW + 32768 + boff);
        bf16x8 bWu = *(const bf16x8*)(SW + 49152 + boff);
        const bf16_t* Ub = SW + 65536;
        bf16x8 bIh = *(const bf16x8*)(Ub + boff);
        bf16x8 bIl = *(const bf16x8*)(Ub + 16384 + boff);
        bf16x8 bFh = *(const bf16x8*)(Ub + 32768 + boff);
        bf16x8 bFl = *(const bf16x8*)(Ub + 49152 + boff);
        bf16x8 bOh = *(const bf16x8*)(Ub + 65536 + boff);
        bf16x8 bOl = *(const bf16x8*)(Ub + 81920 + boff);
        bf16x8 bUh = *(const bf16x8*)(Ub + 98304 + boff);
        bf16x8 bUl = *(const bf16x8*)(Ub + 114688 + boff);

        aI0  = MFMA16(xa0, bWi, aI0);  aI1  = MFMA16(xa1, bWi, aI1);
        aXf0 = MFMA16(xa0, bWf, aXf0); aXf1 = MFMA16(xa1, bWf, aXf1);
        aO0  = MFMA16(xa0, bWo, aO0);  aO1  = MFMA16(xa1, bWo, aO1);
        aU0  = MFMA16(xa0, bWu, aU0);  aU1  = MFMA16(xa1, bWu, aU1);
        aI0 = MFMA16(at0, bIh, aI0); aI0 = MFMA16(at0, bIl, aI0);
        aI1 = MFMA16(at1, bIh, aI1); aI1 = MFMA16(at1, bIl, aI1);
        aO0 = MFMA16(at0, bOh, aO0); aO0 = MFMA16(at0, bOl, aO0);
        aO1 = MFMA16(at1, bOh, aO1); aO1 = MFMA16(at1, bOl, aO1);
        aU0 = MFMA16(at0, bUh, aU0); aU0 = MFMA16(at0, bUl, aU0);
        aU1 = MFMA16(at1, bUh, aU1); aU1 = MFMA16(at1, bUl, aU1);
        aF0 = MFMA16(ac0, bFh, aF0); aF0 = MFMA16(ac0, bFl, aF0);
        aF1 = MFMA16(ac1, bFh, aF1); aF1 = MFMA16(ac1, bFl, aF1);
        aF2 = MFMA16(ac2, bFh, aF2); aF2 = MFMA16(ac2, bFl, aF2);
        aF3 = MFMA16(ac3, bFh, aF3); aF3 = MFMA16(ac3, bFl, aF3);
    }

    const int colg = ct * 16 + lc;
    // children c (LDS bf16)
    float c0v[4][2], c1v[4][2];
#pragma unroll
    for (int m2 = 0; m2 < 4; m2++)
#pragma unroll
        for (int pi = 0; pi < 2; pi++) {
            int pl = m2 * 8 + quad * 2 + pi;
            c0v[m2][pi] = (float)BCc[2 * pl][colg];
            c1v[m2][pi] = (float)BCc[2 * pl + 1][colg];
        }
    // xf (+bias) exchange via wave-private LDS (in-wave RAW; k_lvl-verified)
    float bfv = bf_[colg];
#pragma unroll
    for (int r = 0; r < 4; r++) {
        SCw[quad * 4 + r][lc]      = aXf0[r] + bfv;
        SCw[16 + quad * 4 + r][lc] = aXf1[r] + bfv;
    }
#define NS_FPATH(M2, AF)                                            \
    _Pragma("unroll")                                               \
    for (int pi = 0; pi < 2; pi++) {                                \
        int pl = M2 * 8 + quad * 2 + pi;                            \
        float xf = SCw[pl][lc];                                     \
        float f0 = sigm(xf + AF[2 * pi]);                           \
        float f1 = sigm(xf + AF[2 * pi + 1]);                       \
        SCw[pl][lc] = f0 * c0v[M2][pi] + f1 * c1v[M2][pi];          \
    }
    NS_FPATH(0, aF0) NS_FPATH(1, aF1) NS_FPATH(2, aF2) NS_FPATH(3, aF3)
#undef NS_FPATH
    float bii = bi[colg], boi = bo[colg], bui = bu[colg];
#define NS_IOU(MT, AI, AO, AU)                                      \
    _Pragma("unroll")                                               \
    for (int r = 0; r < 4; r++) {                                   \
        int pl = MT * 16 + quad * 4 + r;                            \
        float iv = sigm(AI[r] + bii);                               \
        float ov = sigm(AO[r] + boi);                               \
        float uv = tanh_(AU[r] + bui);                              \
        float cv = iv * uv + SCw[pl][lc];                           \
        float hv = ov * tanh_(cv);                                  \
        Hg[(size_t)(outBase + pl) * 128 + colg] = (bf16_t)hv;       \
        Cg[(size_t)(outBase + pl) * 128 + colg] = cv;               \
    }
    NS_IOU(0, aI0, aO0, aU0)
    NS_IOU(1, aI1, aO1, aU1)
#undef NS_IOU
}

// ---------------------------------------------------------------------------
// leaf64_wave: ONE wave computes 64 leaf rows x 16 cols (ct), 3 gates.
// 4 kb x {3 loads, 12 MFMAs}; accs 12 f32x4. -> BH/BC rows 0..63.
__device__ __forceinline__ void leaf64_wave(
    const bf16_t* __restrict__ SW,
    const float* __restrict__ bi, const float* __restrict__ bo,
    const float* __restrict__ bu,
    const bf16_t (* __restrict__ XA)[136],
    bf16_t (* __restrict__ BH)[136], bf16_t (* __restrict__ BC)[136],
    int ct, int lane)
{
    const int quad = lane >> 4, lc = lane & 15;
    f32x4 aI[4], aO[4], aU[4];
#pragma unroll
    for (int mt = 0; mt < 4; mt++) {
        aI[mt] = (f32x4){0.f, 0.f, 0.f, 0.f};
        aO[mt] = (f32x4){0.f, 0.f, 0.f, 0.f};
        aU[mt] = (f32x4){0.f, 0.f, 0.f, 0.f};
    }
#pragma unroll
    for (int kb = 0; kb < 4; kb++) {
        const int k0 = kb * 32 + quad * 8;
        bf16x8 a0 = *(const bf16x8*)&XA[lc][k0];
        bf16x8 a1 = *(const bf16x8*)&XA[16 + lc][k0];
        bf16x8 a2 = *(const bf16x8*)&XA[32 + lc][k0];
        bf16x8 a3 = *(const bf16x8*)&XA[48 + lc][k0];
        const size_t boff = ((size_t)(ct * 4 + kb) * 64 + lane) * 8;
        bf16x8 bWi = *(const bf16x8*)(SW + boff);
        bf16x8 bWo = *(const bf16x8*)(SW + 32768 + boff);
        bf16x8 bWu = *(const bf16x8*)(SW + 49152 + boff);
        aI[0] = MFMA16(a0, bWi, aI[0]); aI[1] = MFMA16(a1, bWi, aI[1]);
        aI[2] = MFMA16(a2, bWi, aI[2]); aI[3] = MFMA16(a3, bWi, aI[3]);
        aO[0] = MFMA16(a0, bWo, aO[0]); aO[1] = MFMA16(a1, bWo, aO[1]);
        aO[2] = MFMA16(a2, bWo, aO[2]); aO[3] = MFMA16(a3, bWo, aO[3]);
        aU[0] = MFMA16(a0, bWu, aU[0]); aU[1] = MFMA16(a1, bWu, aU[1]);
        aU[2] = MFMA16(a2, bWu, aU[2]); aU[3] = MFMA16(a3, bWu, aU[3]);
    }
    const int col = ct * 16 + lc;
    float bii = bi[col], boi = bo[col], bui = bu[col];
#pragma unroll
    for (int mt = 0; mt < 4; mt++)
#pragma unroll
        for (int r = 0; r < 4; r++) {
            float iv = sigm(aI[mt][r] + bii);
            float ov = sigm(aO[mt][r] + boi);
            float uv = tanh_(aU[mt][r] + bui);
            float cv = iv * uv;
            int pl = mt * 16 + quad * 4 + r;
            BH[pl][col] = (bf16_t)(ov * tanh_(cv));
            BC[pl][col] = (bf16_t)cv;
        }
}

// ---------------------------------------------------------------------------
// k_pairleaf2: 512 thr, 8 waves (wave = col-tile). Block = 32 L(depth-1)
// parents; phase 1 computes their 64 leaf children (leaf64_wave), phase 2
// the parents (node32_wave, children in LDS). Always full validity.
// LDS: XA[64][136] @0 | BH[64][136] @17408 | BC[64][136] @34816 |
//      SC[8][32][17]f32 @52224. Total 69632.
__global__ __launch_bounds__(512)
void k_pairleaf2(const float* __restrict__ x, const bf16_t* __restrict__ SW,
                 const float* __restrict__ bi, const float* __restrict__ bf_,
                 const float* __restrict__ bo, const float* __restrict__ bu,
                 bf16_t* __restrict__ H, float* __restrict__ C, int Pa)
{
    __shared__ __align__(16) char smem[69632];
    bf16_t (*XA)[136] = (bf16_t(*)[136])(smem);
    bf16_t (*BH)[136] = (bf16_t(*)[136])(smem + 17408);
    bf16_t (*BC)[136] = (bf16_t(*)[136])(smem + 34816);
    float  (*SC)[32][17] = (float(*)[32][17])(smem + 52224);

    const int tid = threadIdx.x;
    const int wave = tid >> 6, lane = tid & 63;
    const int sA0 = Pa + 32 * blockIdx.x;

    {   // stage 64 leaf x rows (shifted leaf base 2*sA0; x row = shifted-1)
        int r = tid >> 3, cb = (tid & 7) * 16;
        cvt16(x + (size_t)(2 * sA0 - 1 + r) * 128 + cb, &XA[r][cb]);
    }
    __syncthreads();
    leaf64_wave(SW, bi, bo, bu, (const bf16_t(*)[136])XA, BH, BC, wave, lane);
    __syncthreads();
    {   // stage 32 parent x rows
        int r = tid >> 3, cb = (tid & 7) * 16;
        if (r < 32) cvt16(x + (size_t)(sA0 - 1 + r) * 128 + cb, &XA[r][cb]);
    }
    __syncthreads();
    node32_wave(SW, bi, bf_, bo, bu,
                (const bf16_t(*)[136])XA, (const bf16_t(*)[136])BH,
                (const bf16_t(*)[136])BC,
                SC[wave], wave,
                H, C, sA0, lane);
}

// ---------------------------------------------------------------------------
// compute32 + internal k_pair: VERIFIED R8/R9 versions, unchanged.
__device__ __forceinline__ void compute32(
    const float* __restrict__ x, const bf16_t* __restrict__ SW,
    const float* __restrict__ bi, const float* __restrict__ bf_,
    const float* __restrict__ bo, const float* __restrict__ bu,
    bf16_t (* __restrict__ XA)[136], float (* __restrict__ SC)[132],
    const bf16_t (* __restrict__ CH)[136],
    const float* __restrict__ Cglob, int ccBase,
    const bf16_t (* __restrict__ BCc)[136], bool ccLds,
    int xRowBase, int valid,
    bf16_t (* __restrict__ BHo)[136], bf16_t (* __restrict__ BCo)[136], int outRowOff,
    bf16_t* __restrict__ Hg, float* __restrict__ Cg, int outBase,
    bf16_t (* __restrict__ Hd)[136], bool outLds, int tid)
{
    {
        int r = tid >> 3, cb = (tid & 7) * 16;
        if (r < valid) cvt16(x + (size_t)(xRowBase + r - 1) * 128 + cb, &XA[r][cb]);
        else           zero16(&XA[r][cb]);
    }
    __syncthreads();

    const int wave = tid >> 6, lane = tid & 63;
    const int quad = lane >> 4, lc = lane & 15;

    f32x4 aI[2][2], aO[2][2], aU[2][2], aXf[2][2], aF[2][4];
#pragma unroll
    for (int nt = 0; nt < 2; nt++) {
#pragma unroll
        for (int mt = 0; mt < 2; mt++) {
            aI[nt][mt]  = (f32x4){0.f, 0.f, 0.f, 0.f};
            aO[nt][mt]  = (f32x4){0.f, 0.f, 0.f, 0.f};
            aU[nt][mt]  = (f32x4){0.f, 0.f, 0.f, 0.f};
            aXf[nt][mt] = (f32x4){0.f, 0.f, 0.f, 0.f};
        }
#pragma unroll
        for (int mt = 0; mt < 4; mt++) aF[nt][mt] = (f32x4){0.f, 0.f, 0.f, 0.f};
    }

    for (int kb = 0; kb < 4; kb++) {
        const int k0 = kb * 32 + quad * 8;
        bf16x8 xa0 = *(const bf16x8*)&XA[lc][k0];
        bf16x8 xa1 = *(const bf16x8*)&XA[16 + lc][k0];
        bf16x8 h00 = *(const bf16x8*)&CH[2 * lc][k0];
        bf16x8 h01 = *(const bf16x8*)&CH[2 * lc + 1][k0];
        bf16x8 h10 = *(const bf16x8*)&CH[2 * lc + 32][k0];
        bf16x8 h11 = *(const bf16x8*)&CH[2 * lc + 33][k0];
        bf16x8 at0, at1;
#pragma unroll
        for (int j = 0; j < 8; j++) {
            at0[j] = (bf16_t)((float)h00[j] + (float)h01[j]);
            at1[j] = (bf16_t)((float)h10[j] + (float)h11[j]);
        }
        bf16x8 ac0 = *(const bf16x8*)&CH[lc][k0];
        bf16x8 ac1 = *(const bf16x8*)&CH[16 + lc][k0];
        bf16x8 ac2 = *(const bf16x8*)&CH[32 + lc][k0];
        bf16x8 ac3 = *(const bf16x8*)&CH[48 + lc][k0];
#pragma unroll
        for (int nt = 0; nt < 2; nt++) {
            const size_t boff = ((size_t)((2 * wave + nt) * 4 + kb) * 64 + lane) * 8;
            bf16x8 bWi = *(const bf16x8*)(SW + boff);
            bf16x8 bWf = *(const bf16x8*)(SW + 16384 + boff);
            bf16x8 bWo = *(const bf16x8*)(SW + 32768 + boff);
            bf16x8 bWu = *(const bf16x8*)(SW + 49152 + boff);
            aI[nt][0]  = MFMA16(xa0, bWi, aI[nt][0]);
            aI[nt][1]  = MFMA16(xa1, bWi, aI[nt][1]);
            aXf[nt][0] = MFMA16(xa0, bWf, aXf[nt][0]);
            aXf[nt][1] = MFMA16(xa1, bWf, aXf[nt][1]);
            aO[nt][0]  = MFMA16(xa0, bWo, aO[nt][0]);
            aO[nt][1]  = MFMA16(xa1, bWo, aO[nt][1]);
            aU[nt][0]  = MFMA16(xa0, bWu, aU[nt][0]);
            aU[nt][1]  = MFMA16(xa1, bWu, aU[nt][1]);
            const bf16_t* Ub = SW + 65536;
            bf16x8 bIh = *(const bf16x8*)(Ub + boff);
            bf16x8 bIl = *(const bf16x8*)(Ub + 16384 + boff);
            aI[nt][0] = MFMA16(at0, bIh, aI[nt][0]);
            aI[nt][0] = MFMA16(at0, bIl, aI[nt][0]);
            aI[nt][1] = MFMA16(at1, bIh, aI[nt][1]);
            aI[nt][1] = MFMA16(at1, bIl, aI[nt][1]);
            bf16x8 bOh = *(const bf16x8*)(Ub + 65536 + boff);
            bf16x8 bOl = *(const bf16x8*)(Ub + 81920 + boff);
            aO[nt][0] = MFMA16(at0, bOh, aO[nt][0]);
            aO[nt][0] = MFMA16(at0, bOl, aO[nt][0]);
            aO[nt][1] = MFMA16(at1, bOh, aO[nt][1]);
            aO[nt][1] = MFMA16(at1, bOl, aO[nt][1]);
            bf16x8 bUh = *(const bf16x8*)(Ub + 98304 + boff);
            bf16x8 bUl = *(const bf16x8*)(Ub + 114688 + boff);
            aU[nt][0] = MFMA16(at0, bUh, aU[nt][0]);
            aU[nt][0] = MFMA16(at0, bUl, aU[nt][0]);
            aU[nt][1] = MFMA16(at1, bUh, aU[nt][1]);
            aU[nt][1] = MFMA16(at1, bUl, aU[nt][1]);
            bf16x8 bFh = *(const bf16x8*)(Ub + 32768 + boff);
            bf16x8 bFl = *(const bf16x8*)(Ub + 49152 + boff);
            aF[nt][0] = MFMA16(ac0, bFh, aF[nt][0]);
            aF[nt][0] = MFMA16(ac0, bFl, aF[nt][0]);
            aF[nt][1] = MFMA16(ac1, bFh, aF[nt][1]);
            aF[nt][1] = MFMA16(ac1, bFl, aF[nt][1]);
            aF[nt][2] = MFMA16(ac2, bFh, aF[nt][2]);
            aF[nt][2] = MFMA16(ac2, bFl, aF[nt][2]);
            aF[nt][3] = MFMA16(ac3, bFh, aF[nt][3]);
            aF[nt][3] = MFMA16(ac3, bFl, aF[nt][3]);
        }
    }
    __syncthreads();   // XA/CH-staging reads done; SC (alias) becomes writable

#pragma unroll
    for (int nt = 0; nt < 2; nt++) {
        const int col = (2 * wave + nt) * 16 + lc;
        float bfv = bf_[col];
#pragma unroll
        for (int mt = 0; mt < 2; mt++)
#pragma unroll
            for (int r = 0; r < 4; r++)
                SC[mt * 16 + quad * 4 + r][col] = aXf[nt][mt][r] + bfv;
    }
    __syncthreads();

    float Sv[2][4][2];
#pragma unroll
    for (int nt = 0; nt < 2; nt++) {
        const int col = (2 * wave + nt) * 16 + lc;
#pragma unroll
        for (int mt = 0; mt < 4; mt++)
#pragma unroll
            for (int pi = 0; pi < 2; pi++) {
                int pl = mt * 8 + quad * 2 + pi;
                float xf = SC[pl][col];
                float f0 = sigm(xf + aF[nt][mt][2 * pi]);
                float f1 = sigm(xf + aF[nt][mt][2 * pi + 1]);
                float c0, c1;
                if (ccLds) {
                    c0 = (float)BCc[2 * pl][col];
                    c1 = (float)BCc[2 * pl + 1][col];
                } else {
                    size_t cr = (size_t)(ccBase + 2 * pl) * 128 + col;
                    c0 = Cglob[cr];
                    c1 = Cglob[cr + 128];
                }
                Sv[nt][mt][pi] = f0 * c0 + f1 * c1;
            }
    }
    __syncthreads();
#pragma unroll
    for (int nt = 0; nt < 2; nt++) {
        const int col = (2 * wave + nt) * 16 + lc;
#pragma unroll
        for (int mt = 0; mt < 4; mt++)
#pragma unroll
            for (int pi = 0; pi < 2; pi++)
                SC[mt * 8 + quad * 2 + pi][col] = Sv[nt][mt][pi];
    }
    __syncthreads();

    float hr[2][2][4];
#pragma unroll
    for (int nt = 0; nt < 2; nt++) {
        const int col = (2 * wave + nt) * 16 + lc;
        float bii = bi[col], boi = bo[col], bui = bu[col];
#pragma unroll
        for (int mt = 0; mt < 2; mt++)
#pragma unroll
            for (int r = 0; r < 4; r++) {
                int pl = mt * 16 + quad * 4 + r;
                float iv = sigm(aI[nt][mt][r] + bii);
                float ov = sigm(aO[nt][mt][r] + boi);
                float uv = tanh_(aU[nt][mt][r] + bui);
                float cv = iv * uv + SC[pl][col];
                float hv = ov * tanh_(cv);
                hr[nt][mt][r] = hv;
                if (outLds) {
                    BHo[outRowOff + pl][col] = (bf16_t)hv;
                    BCo[outRowOff + pl][col] = (bf16_t)cv;
                } else if (pl < valid) {
                    Cg[(size_t)(outBase + pl) * 128 + col] = cv;
                }
            }
    }
    if (outLds) {
        __syncthreads();
    } else {
        __syncthreads();
#pragma unroll
        for (int nt = 0; nt < 2; nt++) {
            const int col = (2 * wave + nt) * 16 + lc;
#pragma unroll
            for (int mt = 0; mt < 2; mt++)
#pragma unroll
                for (int r = 0; r < 4; r++)
                    Hd[mt * 16 + quad * 4 + r][col] = (bf16_t)hr[nt][mt][r];
        }
        __syncthreads();
        int r = tid >> 3, cb = (tid & 7) * 16;
        if (r < valid) {
            uint4* dst = (uint4*)(Hg + (size_t)(outBase + r) * 128 + cb);
            dst[0] = *(uint4*)&Hd[r][cb];
            dst[1] = *(uint4*)&Hd[r][cb + 8];
        }
        __syncthreads();
    }
}

__global__ __launch_bounds__(256)
void k_pair(const float* __restrict__ x, const bf16_t* __restrict__ SW,
            const float* __restrict__ bi, const float* __restrict__ bf_,
            const float* __restrict__ bo, const float* __restrict__ bu,
            bf16_t* __restrict__ H, float* __restrict__ C,
            int Pa)
{
    __shared__ __align__(16) char smem[60928];
    bf16_t (*XA)[136] = (bf16_t(*)[136])(smem);
    bf16_t (*HC)[136] = (bf16_t(*)[136])(smem + 8704);
    float  (*SC)[132] = (float(*)[132])(smem);
    bf16_t (*BH)[136] = (bf16_t(*)[136])(smem + 26112);
    bf16_t (*BC)[136] = (bf16_t(*)[136])(smem + 43520);

    const int tid = threadIdx.x;
    const int t   = blockIdx.x;
    const int sA0 = Pa + 32 * t;
    int Pta = Pa - 32 * t; if (Pta > 32) Pta = 32;

    if (Pta < 32) {
        bf16x8 z = (bf16x8)(bf16_t)0.f;
        for (int i = tid; i < 64 * 17; i += 256) {
            ((bf16x8*)BH)[i] = z;
            ((bf16x8*)BC)[i] = z;
        }
    }

    for (int q = 0; q < 2; q++) {
        int bvalid = 2 * Pa - (64 * t + 32 * q);
        if (bvalid > 32) bvalid = 32;
        if (bvalid <= 0) break;
        {
            int r = tid >> 2, cb = (tid & 3) * 32;
            if (r < 2 * bvalid) {
                const uint4* src = (const uint4*)(H + (size_t)(4 * sA0 + 64 * q + r) * 128 + cb);
                *(uint4*)&HC[r][cb]      = src[0];
                *(uint4*)&HC[r][cb + 8]  = src[1];
                *(uint4*)&HC[r][cb + 16] = src[2];
                *(uint4*)&HC[r][cb + 24] = src[3];
            } else {
                uint4 z = {0u, 0u, 0u, 0u};
                *(uint4*)&HC[r][cb]      = z;
                *(uint4*)&HC[r][cb + 8]  = z;
                *(uint4*)&HC[r][cb + 16] = z;
                *(uint4*)&HC[r][cb + 24] = z;
            }
        }
        compute32(x, SW, bi, bf_, bo, bu, XA, SC,
                  (const bf16_t(*)[136])HC,
                  C, 4 * sA0 + 64 * q, nullptr, false,
                  2 * sA0 + 32 * q, bvalid,
                  BH, BC, 32 * q,
                  nullptr, nullptr, 0, nullptr, true, tid);
    }

    compute32(x, SW, bi, bf_, bo, bu, XA, SC,
              (const bf16_t(*)[136])BH,
              nullptr, 0, (const bf16_t(*)[136])BC, true,
              sA0, Pta,
              nullptr, nullptr, 0,
              H, C, sA0, HC, false, tid);
}

// ---------------------------------------------------------------------------
// k_lvl: VERIFIED R5 version, unchanged.
__global__ __launch_bounds__(256, 2)
void k_lvl(const float* __restrict__ x, const bf16_t* __restrict__ SW,
           const float* __restrict__ bi, const float* __restrict__ bf_,
           const float* __restrict__ bo, const float* __restrict__ bu,
           bf16_t* H, float* C, int np)
{
    __shared__ __align__(16) char smem[75264];
    f32x4  (*PR)[4][64] = (f32x4(*)[4][64])smem;
    bf16_t (*XA)[136]   = (bf16_t(*)[136])(smem + 49152);
    bf16_t (*CH)[136]   = (bf16_t(*)[136])(smem + 57856);
    float  (*SC)[17]    = (float(*)[17])smem;

    const int tid = threadIdx.x;
    const int wave = tid >> 6, lane = tid & 63;
    const int quad = lane >> 4, lc = lane & 15;

    const int task = blockIdx.x;
    const int ct = task & 7, mt = task >> 3;
    int valid = np - 32 * mt; if (valid > 32) valid = 32;
    if (valid <= 0) return;
    const int prow = np + 32 * mt;
    const int crow = 2 * np + 64 * mt;

    {   // stage XA
        int r = tid >> 3, cb = (tid & 7) * 16;
        if (r < valid) cvt16(x + (size_t)(prow - 1 + r) * 128 + cb, &XA[r][cb]);
        else           zero16(&XA[r][cb]);
    }
    {   // stage CH
        int r = tid >> 2, cb = (tid & 3) * 32;
        if (r < 2 * valid) {
            const uint4* src = (const uint4*)(H + (size_t)(crow + r) * 128 + cb);
            *(uint4*)&CH[r][cb]      = src[0];
            *(uint4*)&CH[r][cb + 8]  = src[1];
            *(uint4*)&CH[r][cb + 16] = src[2];
            *(uint4*)&CH[r][cb + 24] = src[3];
        } else {
            uint4 z = {0u, 0u, 0u, 0u};
            *(uint4*)&CH[r][cb]      = z;
            *(uint4*)&CH[r][cb + 8]  = z;
            *(uint4*)&CH[r][cb + 16] = z;
            *(uint4*)&CH[r][cb + 24] = z;
        }
    }
    __syncthreads();

    f32x4 z4 = (f32x4){0.f, 0.f, 0.f, 0.f};
    f32x4 aI0 = z4, aI1 = z4, aXf0 = z4, aXf1 = z4;
    f32x4 aO0 = z4, aO1 = z4, aU0 = z4, aU1 = z4;
    f32x4 aF0 = z4, aF1 = z4, aF2 = z4, aF3 = z4;
    {
        const int k0 = wave * 32 + quad * 8;
        bf16x8 xa0 = *(const bf16x8*)&XA[lc][k0];
        bf16x8 xa1 = *(const bf16x8*)&XA[16 + lc][k0];
        bf16x8 h00 = *(const bf16x8*)&CH[2 * lc][k0];
        bf16x8 h01 = *(const bf16x8*)&CH[2 * lc + 1][k0];
        bf16x8 h10 = *(const bf16x8*)&CH[2 * lc + 32][k0];
        bf16x8 h11 = *(const bf16x8*)&CH[2 * lc + 33][k0];
        bf16x8 at0, at1;
#pragma unroll
        for (int j = 0; j < 8; j++) {
            at0[j] = (bf16_t)((float)h00[j] + (float)h01[j]);
            at1[j] = (bf16_t)((float)h10[j] + (float)h11[j]);
        }
        bf16x8 ac0 = *(const bf16x8*)&CH[lc][k0];
        bf16x8 ac1 = *(const bf16x8*)&CH[16 + lc][k0];
        bf16x8 ac2 = *(const bf16x8*)&CH[32 + lc][k0];
        bf16x8 ac3 = *(const bf16x8*)&CH[48 + lc][k0];

        const size_t boff = ((size_t)(ct * 4 + wave) * 64 + lane) * 8;
        bf16x8 bWi = *(const bf16x8*)(SW + boff);
        bf16x8 bWf = *(const bf16x8*)(SW + 16384 + boff);
        bf16x8 bWo = *(const bf16x8*)(SW + 32768 + boff);
        bf16x8 bWu = *(const bf16x8*)(SW + 49152 + boff);
        const bf16_t* Ub = SW + 65536;
        bf16x8 bIh = *(const bf16x8*)(Ub + boff);
        bf16x8 bIl = *(const bf16x8*)(Ub + 16384 + boff);
        bf16x8 bFh = *(const bf16x8*)(Ub + 32768 + boff);
        bf16x8 bFl = *(const bf16x8*)(Ub + 49152 + boff);
        bf16x8 bOh = *(const bf16x8*)(Ub + 65536 + boff);
        bf16x8 bOl = *(const bf16x8*)(Ub + 81920 + boff);
        bf16x8 bUh = *(const bf16x8*)(Ub + 98304 + boff);
        bf16x8 bUl = *(const bf16x8*)(Ub + 114688 + boff);

        aI0  = MFMA16(xa0, bWi, aI0);  aI1  = MFMA16(xa1, bWi, aI1);
        aXf0 = MFMA16(xa0, bWf, aXf0); aXf1 = MFMA16(xa1, bWf, aXf1);
        aO0  = MFMA16(xa0, bWo, aO0);  aO1  = MFMA16(xa1, bWo, aO1);
        aU0  = MFMA16(xa0, bWu, aU0);  aU1  = MFMA16(xa1, bWu, aU1);
        aI0 = MFMA16(at0, bIh, aI0); aI0 = MFMA16(at0, bIl, aI0);
        aI1 = MFMA16(at1, bIh, aI1); aI1 = MFMA16(at1, bIl, aI1);
        aO0 = MFMA16(at0, bOh, aO0); aO0 = MFMA16(at0, bOl, aO0);
        aO1 = MFMA16(at1, bOh, aO1); aO1 = MFMA16(at1, bOl, aO1);
        aU0 = MFMA16(at0, bUh, aU0); aU0 = MFMA16(at0, bUl, aU0);
        aU1 = MFMA16(at1, bUh, aU1); aU1 = MFMA16(at1, bUl, aU1);
        aF0 = MFMA16(ac0, bFh, aF0); aF0 = MFMA16(ac0, bFl, aF0);
        aF1 = MFMA16(ac1, bFh, aF1); aF1 = MFMA16(ac1, bFl, aF1);
        aF2 = MFMA16(ac2, bFh, aF2); aF2 = MFMA16(ac2, bFl, aF2);
        aF3 = MFMA16(ac3, bFh, aF3); aF3 = MFMA16(ac3, bFl, aF3);
    }
    if (wave != 0) {
        PR[0][wave][lane]  = aI0;  PR[1][wave][lane]  = aI1;
        PR[2][wave][lane]  = aXf0; PR[3][wave][lane]  = aXf1;
        PR[4][wave][lane]  = aO0;  PR[5][wave][lane]  = aO1;
        PR[6][wave][lane]  = aU0;  PR[7][wave][lane]  = aU1;
        PR[8][wave][lane]  = aF0;  PR[9][wave][lane]  = aF1;
        PR[10][wave][lane] = aF2;  PR[11][wave][lane] = aF3;
    }
    __syncthreads();
    if (wave == 0) {
        aI0  += PR[0][1][lane]  + PR[0][2][lane]  + PR[0][3][lane];
        aI1  += PR[1][1][lane]  + PR[1][2][lane]  + PR[1][3][lane];
        aXf0 += PR[2][1][lane]  + PR[2][2][lane]  + PR[2][3][lane];
        aXf1 += PR[3][1][lane]  + PR[3][2][lane]  + PR[3][3][lane];
        aO0  += PR[4][1][lane]  + PR[4][2][lane]  + PR[4][3][lane];
        aO1  += PR[5][1][lane]  + PR[5][2][lane]  + PR[5][3][lane];
        aU0  += PR[6][1][lane]  + PR[6][2][lane]  + PR[6][3][lane];
        aU1  += PR[7][1][lane]  + PR[7][2][lane]  + PR[7][3][lane];
        aF0  += PR[8][1][lane]  + PR[8][2][lane]  + PR[8][3][lane];
        aF1  += PR[9][1][lane]  + PR[9][2][lane]  + PR[9][3][lane];
        aF2  += PR[10][1][lane] + PR[10][2][lane] + PR[10][3][lane];
        aF3  += PR[11][1][lane] + PR[11][2][lane] + PR[11][3][lane];

        const int colg = ct * 16 + lc;
        float c0v[4][2], c1v[4][2];
#pragma unroll
        for (int m2 = 0; m2 < 4; m2++)
#pragma unroll
            for (int pi = 0; pi < 2; pi++) {
                int pl = m2 * 8 + quad * 2 + pi;
                size_t cr = (size_t)(crow + 2 * pl) * 128 + colg;
                c0v[m2][pi] = C[cr];
                c1v[m2][pi] = C[cr + 128];
            }
        float bfv = bf_[colg];
#pragma unroll
        for (int r = 0; r < 4; r++) {
            SC[quad * 4 + r][lc]      = aXf0[r] + bfv;
            SC[16 + quad * 4 + r][lc] = aXf1[r] + bfv;
        }
#define NS_FPATH(M2, AF)                                            \
        _Pragma("unroll")                                           \
        for (int pi = 0; pi < 2; pi++) {                            \
            int pl = M2 * 8 + quad * 2 + pi;                        \
            float xf = SC[pl][lc];                                  \
            float f0 = sigm(xf + AF[2 * pi]);                       \
            float f1 = sigm(xf + AF[2 * pi + 1]);                   \
            SC[pl][lc] = f0 * c0v[M2][pi] + f1 * c1v[M2][pi];       \
        }
        NS_FPATH(0, aF0) NS_FPATH(1, aF1) NS_FPATH(2, aF2) NS_FPATH(3, aF3)
#undef NS_FPATH
        float bii = bi[colg], boi = bo[colg], bui = bu[colg];
#define NS_IOU(MT, AI, AO, AU)                                      \
        _Pragma("unroll")                                           \
        for (int r = 0; r < 4; r++) {                               \
            int pl = MT * 16 + quad * 4 + r;                        \
            float iv = sigm(AI[r] + bii);                           \
            float ov = sigm(AO[r] + boi);                           \
            float uv = tanh_(AU[r] + bui);                          \
            float cv = iv * uv + SC[pl][lc];                        \
            if (pl < valid) {                                       \
                H[(size_t)(prow + pl) * 128 + colg] = (bf16_t)(ov * tanh_(cv)); \
                C[(size_t)(prow + pl) * 128 + colg] = cv;           \
            }                                                       \
        }
        NS_IOU(0, aI0, aO0, aU0)
        NS_IOU(1, aI1, aO1, aU1)
#undef NS_IOU
    }
}

__global__ __launch_bounds__(256)
void k_out(const bf16_t* __restrict__ H, const float* __restrict__ C,
           float* __restrict__ out)
{
    int t = threadIdx.x;
    if (t < 128)      out[t] = (float)H[128 + t];   // shifted row 1 = root
    else if (t < 256) out[t] = C[t];                // C[128 + (t-128)]
}

// ---------------------------------------------------------------------------
extern "C" void kernel_launch(void* const* d_in, const int* in_sizes, int n_in,
                              void* d_out, int out_size, void* d_ws, size_t ws_size,
                              hipStream_t stream)
{
    const float* x   = (const float*)d_in[0];
    const float* Wi  = (const float*)d_in[1];
    const float* bi  = (const float*)d_in[2];
    const float* Ui  = (const float*)d_in[3];
    const float* Wf  = (const float*)d_in[4];
    const float* bf_ = (const float*)d_in[5];
    const float* Uf  = (const float*)d_in[6];
    const float* Wo  = (const float*)d_in[7];
    const float* bo  = (const float*)d_in[8];
    const float* Uo  = (const float*)d_in[9];
    const float* Wu  = (const float*)d_in[10];
    const float* bu  = (const float*)d_in[11];
    const float* Uu  = (const float*)d_in[12];

    int Ntot  = in_sizes[0] / 128;
    int depth = 31 - __builtin_clz((unsigned)(Ntot + 1)) - 1;

    // workspace: SW 384 KB | H bf16 (Ntot+1)*128 | C fp32 (Ntot+1)*128
    char* w = (char*)d_ws;
    bf16_t* SW = (bf16_t*)w;  w += 393216;
    bf16_t* H  = (bf16_t*)w;  w += (size_t)(Ntot + 1) * 128 * sizeof(bf16_t);
    float*  C  = (float*)w;

    k_prep<<<8, 256, 0, stream>>>(Wi, Wf, Wo, Wu, Ui, Uf, Uo, Uu, SW);

    {   // levels depth + depth-1 (leaves fused), wave-per-col-tile
        int Pa = 1 << (depth - 1);
        k_pairleaf2<<<Pa / 32, 512, 0, stream>>>(x, SW, bi, bf_, bo, bu, H, C, Pa);
    }
    int lowest = depth - 1;
    for (int A = depth - 3; A >= 14; A -= 2) {   // big internal pairs (verified)
        int Pa = 1 << A;
        int blocks = (Pa + 31) / 32;
        k_pair<<<blocks, 256, 0, stream>>>(x, SW, bi, bf_, bo, bu, H, C, Pa);
        lowest = A;
    }
    // remaining levels: one latency-optimized launch per level (verified)
    for (int l = lowest - 1; l >= 0; l--) {
        int np = 1 << l;
        int nmt = (np + 31) / 32;
        k_lvl<<<nmt * 8, 256, 0, stream>>>(x, SW, bi, bf_, bo, bu, H, C, np);
    }
    k_out<<<1, 256, 0, stream>>>(H, C, (float*)d_out);
}